// Round 1
// baseline (720.347 us; speedup 1.0000x reference)
//
#include <hip/hip_runtime.h>
#include <hip/hip_bf16.h>
#include <type_traits>

#define N_NODES 50000
#define N_EDGES 800000
#define DIM     128
#define N_BATCH 25000

typedef unsigned short u16;
typedef unsigned int   u32;

static __device__ __forceinline__ float bf2f(u16 u) {
    union { u32 i; float f; } v; v.i = ((u32)u) << 16; return v.f;
}
static __device__ __forceinline__ u16 f2bf(float f) {
    union { float f; u32 i; } v; v.f = f;
    u32 x = v.i;
    u32 r = x + 0x7fffu + ((x >> 16) & 1u);   // RTNE
    return (u16)(r >> 16);
}

// ---------------- CSR build ----------------

__global__ void k_zero(int* deg, float* accum) {
    int i = blockIdx.x * 256 + threadIdx.x;
    if (i < N_NODES) deg[i] = 0;
    if (i == 0) accum[0] = 0.f;
}

__global__ void k_hist(const int* dst, int* deg) {
    int e = blockIdx.x * 256 + threadIdx.x;
    if (e < N_EDGES) atomicAdd(&deg[dst[e]], 1);
}

__global__ void k_block_sums(const int* deg, int* bsums) {
    __shared__ int sh[512];
    int i = blockIdx.x * 512 + threadIdx.x;
    sh[threadIdx.x] = (i < N_NODES) ? deg[i] : 0;
    __syncthreads();
    for (int off = 256; off > 0; off >>= 1) {
        if (threadIdx.x < off) sh[threadIdx.x] += sh[threadIdx.x + off];
        __syncthreads();
    }
    if (threadIdx.x == 0) bsums[blockIdx.x] = sh[0];
}

__global__ void k_scan_bsums(const int* bsums, int* boffs, int nb) {
    if (threadIdx.x == 0) {
        int run = 0;
        for (int i = 0; i < nb; ++i) { boffs[i] = run; run += bsums[i]; }
    }
}

__global__ void k_scan_final(const int* deg, const int* boffs,
                             int* row_ptr, int* cursor, float* deg_inv) {
    __shared__ int sh[512];
    int i = blockIdx.x * 512 + threadIdx.x;
    int v = (i < N_NODES) ? deg[i] : 0;
    sh[threadIdx.x] = v;
    __syncthreads();
    for (int off = 1; off < 512; off <<= 1) {
        int x = (threadIdx.x >= (unsigned)off) ? sh[threadIdx.x - off] : 0;
        __syncthreads();
        sh[threadIdx.x] += x;
        __syncthreads();
    }
    if (i < N_NODES) {
        int excl = sh[threadIdx.x] - v + boffs[blockIdx.x];
        row_ptr[i] = excl;
        cursor[i]  = excl;
        deg_inv[i] = 1.0f / (float)(v < 1 ? 1 : v);
    }
}

__global__ void k_scatter(const int* src, const int* dst, int* cursor, int* csr_src) {
    int e = blockIdx.x * 256 + threadIdx.x;
    if (e < N_EDGES) {
        int d = dst[e];
        int pos = atomicAdd(&cursor[d], 1);
        csr_src[pos] = src[e];
    }
}

// ---------------- weight transpose (W[j][k] -> WT[k][j]) ----------------

__global__ void k_transpose(const float* W, float* WT) {
    int i = blockIdx.x * 256 + threadIdx.x;   // 16384 elements
    int k = i >> 7, j = i & 127;
    WT[k * DIM + j] = W[j * DIM + k];
}

// ---------------- mean aggregation (wave per node, 2 dims/lane) ----------------

template <typename Tin>
__global__ void k_aggregate(const Tin* __restrict__ h, const int* __restrict__ csr_src,
                            const int* __restrict__ row_ptr, const int* __restrict__ deg,
                            const float* __restrict__ deg_inv, u16* __restrict__ agg) {
    int gid  = blockIdx.x * 256 + threadIdx.x;
    int node = gid >> 6;
    int lane = threadIdx.x & 63;
    if (node >= N_NODES) return;
    int start = __builtin_amdgcn_readfirstlane(row_ptr[node]);
    int cnt   = __builtin_amdgcn_readfirstlane(deg[node]);
    float a0 = 0.f, a1 = 0.f;
    for (int e = 0; e < cnt; ++e) {
        int s = __builtin_amdgcn_readfirstlane(csr_src[start + e]);
        int base = s * DIM + lane * 2;
        if constexpr (std::is_same<Tin, float>::value) {
            float2 v = *(const float2*)(h + base);
            a0 += v.x; a1 += v.y;
        } else {
            u32 u = *(const u32*)((const u16*)h + base);
            a0 += bf2f((u16)(u & 0xffffu));
            a1 += bf2f((u16)(u >> 16));
        }
    }
    float inv = deg_inv[node];
    a0 *= inv; a1 *= inv;
    u32 out = (u32)f2bf(a0) | ((u32)f2bf(a1) << 16);
    *(u32*)(agg + node * DIM + lane * 2) = out;
}

// ---------------- fused SAGE linear: out = act(agg@Wl^T + b + h@Wr^T) ----------------
// Block: 256 threads, 32 rows x 128 cols tile. Thread (tr=t>>4, tc=t&15)
// computes rows {2tr,2tr+1} x cols [8tc,8tc+8). LDS row stride 129 (pad).

template <bool RELU, typename Tin>
__global__ void k_gemm(const u16* __restrict__ agg, const Tin* __restrict__ h,
                       const float* __restrict__ WlT, const float* __restrict__ WrT,
                       const float* __restrict__ bias, u16* __restrict__ out) {
    __shared__ float aS[32 * 129];
    __shared__ float hS[32 * 129];
    int rowBase = blockIdx.x * 32;
    for (int i = threadIdx.x; i < 32 * DIM; i += 256) {
        int r = i >> 7, c = i & 127;
        int gr = rowBase + r;
        float va = 0.f, vh = 0.f;
        if (gr < N_NODES) {
            int g = gr * DIM + c;
            va = bf2f(agg[g]);
            if constexpr (std::is_same<Tin, float>::value) vh = h[g];
            else vh = bf2f(h[g]);
        }
        aS[r * 129 + c] = va;
        hS[r * 129 + c] = vh;
    }
    __syncthreads();

    int tr = threadIdx.x >> 4, tc = threadIdx.x & 15;
    int r0 = tr * 2, r1 = r0 + 1;
    int cbase = tc * 8;
    float acc0[8], acc1[8];
#pragma unroll
    for (int j = 0; j < 8; ++j) { float b = bias[cbase + j]; acc0[j] = b; acc1[j] = b; }

    for (int k = 0; k < DIM; ++k) {
        float a0 = aS[r0 * 129 + k], a1 = aS[r1 * 129 + k];
        float h0 = hS[r0 * 129 + k], h1 = hS[r1 * 129 + k];
        const float4* wl = (const float4*)(WlT + k * DIM + cbase);
        const float4* wr = (const float4*)(WrT + k * DIM + cbase);
        float4 wl0 = wl[0], wl1 = wl[1];
        float4 wr0 = wr[0], wr1 = wr[1];
        float wlv[8] = {wl0.x, wl0.y, wl0.z, wl0.w, wl1.x, wl1.y, wl1.z, wl1.w};
        float wrv[8] = {wr0.x, wr0.y, wr0.z, wr0.w, wr1.x, wr1.y, wr1.z, wr1.w};
#pragma unroll
        for (int j = 0; j < 8; ++j) {
            acc0[j] += a0 * wlv[j] + h0 * wrv[j];
            acc1[j] += a1 * wlv[j] + h1 * wrv[j];
        }
    }

    if (rowBase + r0 < N_NODES) {
#pragma unroll
        for (int j = 0; j < 8; ++j) {
            float v = acc0[j];
            if (RELU) v = fmaxf(v, 0.f);
            out[(rowBase + r0) * DIM + cbase + j] = f2bf(v);
        }
    }
    if (rowBase + r1 < N_NODES) {
#pragma unroll
        for (int j = 0; j < 8; ++j) {
            float v = acc1[j];
            if (RELU) v = fmaxf(v, 0.f);
            out[(rowBase + r1) * DIM + cbase + j] = f2bf(v);
        }
    }
}

// ---------------- head: softmax -> log_softmax -> NLL mean ----------------

__global__ void k_head(const u16* __restrict__ h3, const int* __restrict__ batch,
                       const int* __restrict__ labels, const float* __restrict__ Wlin,
                       const float* __restrict__ blin, float* __restrict__ accum) {
    int gid  = blockIdx.x * 256 + threadIdx.x;
    int wv   = gid >> 6;
    int lane = threadIdx.x & 63;
    float contrib = 0.f;
    if (wv < N_BATCH) {
        int n = batch[wv];
        u32 u = *(const u32*)(h3 + n * DIM + lane * 2);
        float h0 = bf2f((u16)(u & 0xffffu));
        float h1 = bf2f((u16)(u >> 16));
        float w00 = Wlin[lane * 2],       w01 = Wlin[lane * 2 + 1];
        float w10 = Wlin[DIM + lane * 2], w11 = Wlin[DIM + lane * 2 + 1];
        float z0 = h0 * w00 + h1 * w01;
        float z1 = h0 * w10 + h1 * w11;
#pragma unroll
        for (int off = 32; off > 0; off >>= 1) {
            z0 += __shfl_xor(z0, off);
            z1 += __shfl_xor(z1, off);
        }
        z0 += blin[0]; z1 += blin[1];
        // preds = softmax(z)
        float m  = fmaxf(z0, z1);
        float e0 = expf(z0 - m), e1 = expf(z1 - m);
        float s  = e0 + e1;
        float p0 = e0 / s, p1 = e1 / s;
        // logp = log_softmax(preds)
        float m2  = fmaxf(p0, p1);
        float lse = m2 + logf(expf(p0 - m2) + expf(p1 - m2));
        int lab = labels[n];
        float lp = ((lab == 0) ? p0 : p1) - lse;
        contrib = -lp * (1.0f / (float)N_BATCH);
    }
    __shared__ float sh[4];
    if (lane == 0) sh[threadIdx.x >> 6] = contrib;
    __syncthreads();
    if (threadIdx.x == 0) atomicAdd(accum, sh[0] + sh[1] + sh[2] + sh[3]);
}

__global__ void k_finalize(const float* accum, float* out) {
    if (threadIdx.x == 0) out[0] = accum[0];
}

// ---------------- launch ----------------

extern "C" void kernel_launch(void* const* d_in, const int* in_sizes, int n_in,
                              void* d_out, int out_size, void* d_ws, size_t ws_size,
                              hipStream_t stream) {
    const float* x    = (const float*)d_in[0];
    const int*   eidx = (const int*)d_in[1];
    const int*   batch  = (const int*)d_in[2];
    const int*   labels = (const int*)d_in[3];
    const float* W1l = (const float*)d_in[4];
    const float* b1  = (const float*)d_in[5];
    const float* W1r = (const float*)d_in[6];
    const float* W2l = (const float*)d_in[7];
    const float* b2  = (const float*)d_in[8];
    const float* W2r = (const float*)d_in[9];
    const float* W3l = (const float*)d_in[10];
    const float* b3  = (const float*)d_in[11];
    const float* W3r = (const float*)d_in[12];
    const float* Wlin = (const float*)d_in[13];
    const float* blin = (const float*)d_in[14];

    const int* src = eidx;
    const int* dst = eidx + N_EDGES;

    // workspace carve-up (512B aligned)
    size_t off = 0;
    auto alloc = [&](size_t bytes) -> char* {
        off = (off + 511) & ~(size_t)511;
        char* p = (char*)d_ws + off;
        off += bytes;
        return p;
    };
    int*   deg     = (int*)  alloc(N_NODES * 4);
    int*   row_ptr = (int*)  alloc(N_NODES * 4);
    int*   cursor  = (int*)  alloc(N_NODES * 4);
    float* deg_inv = (float*)alloc(N_NODES * 4);
    int*   bsums   = (int*)  alloc(128 * 4);
    int*   boffs   = (int*)  alloc(128 * 4);
    int*   csr_src = (int*)  alloc(N_EDGES * 4);
    float* wT      = (float*)alloc(6 * DIM * DIM * 4);
    u16*   agg     = (u16*)  alloc((size_t)N_NODES * DIM * 2);
    u16*   bufA    = (u16*)  alloc((size_t)N_NODES * DIM * 2);
    u16*   bufB    = (u16*)  alloc((size_t)N_NODES * DIM * 2);
    float* accum   = (float*)alloc(4);

    float* wT1l = wT + 0 * DIM * DIM;
    float* wT1r = wT + 1 * DIM * DIM;
    float* wT2l = wT + 2 * DIM * DIM;
    float* wT2r = wT + 3 * DIM * DIM;
    float* wT3l = wT + 4 * DIM * DIM;
    float* wT3r = wT + 5 * DIM * DIM;

    const int ZB   = (N_NODES + 255) / 256;     // 196
    const int EB   = (N_EDGES + 255) / 256;     // 3125
    const int SB   = (N_NODES + 511) / 512;     // 98
    const int AGGB = N_NODES * 64 / 256;        // 12500
    const int GB   = (N_NODES + 31) / 32;       // 1563
    const int HB   = N_BATCH * 64 / 256;        // 6250
    const int TB   = DIM * DIM / 256;           // 64

    k_zero<<<ZB, 256, 0, stream>>>(deg, accum);
    k_hist<<<EB, 256, 0, stream>>>(dst, deg);
    k_block_sums<<<SB, 512, 0, stream>>>(deg, bsums);
    k_scan_bsums<<<1, 64, 0, stream>>>(bsums, boffs, SB);
    k_scan_final<<<SB, 512, 0, stream>>>(deg, boffs, row_ptr, cursor, deg_inv);
    k_scatter<<<EB, 256, 0, stream>>>(src, dst, cursor, csr_src);

    k_transpose<<<TB, 256, 0, stream>>>(W1l, wT1l);
    k_transpose<<<TB, 256, 0, stream>>>(W1r, wT1r);
    k_transpose<<<TB, 256, 0, stream>>>(W2l, wT2l);
    k_transpose<<<TB, 256, 0, stream>>>(W2r, wT2r);
    k_transpose<<<TB, 256, 0, stream>>>(W3l, wT3l);
    k_transpose<<<TB, 256, 0, stream>>>(W3r, wT3r);

    // layer 1: x (f32) -> bufA
    k_aggregate<float><<<AGGB, 256, 0, stream>>>(x, csr_src, row_ptr, deg, deg_inv, agg);
    k_gemm<true, float><<<GB, 256, 0, stream>>>(agg, x, wT1l, wT1r, b1, bufA);
    // layer 2: bufA -> bufB
    k_aggregate<u16><<<AGGB, 256, 0, stream>>>(bufA, csr_src, row_ptr, deg, deg_inv, agg);
    k_gemm<true, u16><<<GB, 256, 0, stream>>>(agg, bufA, wT2l, wT2r, b2, bufB);
    // layer 3: bufB -> bufA (h3)
    k_aggregate<u16><<<AGGB, 256, 0, stream>>>(bufB, csr_src, row_ptr, deg, deg_inv, agg);
    k_gemm<false, u16><<<GB, 256, 0, stream>>>(agg, bufB, wT3l, wT3r, b3, bufA);

    k_head<<<HB, 256, 0, stream>>>(bufA, batch, labels, Wlin, blin, accum);
    k_finalize<<<1, 64, 0, stream>>>(accum, (float*)d_out);
}

// Round 2
// 404.551 us; speedup vs baseline: 1.7806x; 1.7806x over previous
//
#include <hip/hip_runtime.h>
#include <hip/hip_bf16.h>

#define N_NODES 50000
#define MPAD    50048
#define N_EDGES 800000
#define DIM     128
#define N_BATCH 25000

typedef unsigned short u16;
typedef unsigned int   u32;

typedef __attribute__((ext_vector_type(8))) short bf16x8;
typedef __attribute__((ext_vector_type(4))) float f32x4;

static __device__ __forceinline__ float bf2f(u16 u) {
    union { u32 i; float f; } v; v.i = ((u32)u) << 16; return v.f;
}
static __device__ __forceinline__ u16 f2bf(float f) {
    union { float f; u32 i; } v; v.f = f;
    u32 x = v.i;
    u32 r = x + 0x7fffu + ((x >> 16) & 1u);   // RTNE
    return (u16)(r >> 16);
}

// ---------------- CSR build ----------------

__global__ void k_zero(int* deg, float* accum) {
    int i = blockIdx.x * 256 + threadIdx.x;
    if (i < N_NODES) deg[i] = 0;
    if (i == 0) accum[0] = 0.f;
}

__global__ void k_hist(const int* dst, int* deg) {
    int e = blockIdx.x * 256 + threadIdx.x;
    if (e < N_EDGES) atomicAdd(&deg[dst[e]], 1);
}

__global__ void k_block_sums(const int* deg, int* bsums) {
    __shared__ int sh[512];
    int i = blockIdx.x * 512 + threadIdx.x;
    sh[threadIdx.x] = (i < N_NODES) ? deg[i] : 0;
    __syncthreads();
    for (int off = 256; off > 0; off >>= 1) {
        if (threadIdx.x < off) sh[threadIdx.x] += sh[threadIdx.x + off];
        __syncthreads();
    }
    if (threadIdx.x == 0) bsums[blockIdx.x] = sh[0];
}

__global__ void k_scan_bsums(const int* bsums, int* boffs, int nb) {
    if (threadIdx.x == 0) {
        int run = 0;
        for (int i = 0; i < nb; ++i) { boffs[i] = run; run += bsums[i]; }
    }
}

__global__ void k_scan_final(const int* deg, const int* boffs,
                             int* row_ptr, int* cursor, float* deg_inv) {
    __shared__ int sh[512];
    int i = blockIdx.x * 512 + threadIdx.x;
    int v = (i < N_NODES) ? deg[i] : 0;
    sh[threadIdx.x] = v;
    __syncthreads();
    for (int off = 1; off < 512; off <<= 1) {
        int x = (threadIdx.x >= (unsigned)off) ? sh[threadIdx.x - off] : 0;
        __syncthreads();
        sh[threadIdx.x] += x;
        __syncthreads();
    }
    if (i < N_NODES) {
        int excl = sh[threadIdx.x] - v + boffs[blockIdx.x];
        row_ptr[i] = excl;
        cursor[i]  = excl;
        deg_inv[i] = 1.0f / (float)(v < 1 ? 1 : v);
    }
}

__global__ void k_scatter(const int* src, const int* dst, int* cursor, int* csr_src) {
    int e = blockIdx.x * 256 + threadIdx.x;
    if (e < N_EDGES) {
        int d = dst[e];
        int pos = atomicAdd(&cursor[d], 1);
        csr_src[pos] = src[e];
    }
}

// ---------------- casts ----------------

// x [N_NODES][128] f32 -> [MPAD][128] bf16 (pad rows zeroed)
__global__ void k_cast_x(const float* __restrict__ x, u16* __restrict__ xb) {
    int gid = blockIdx.x * 256 + threadIdx.x;   // MPAD*16 threads, 8 elems each
    int row = gid >> 4;
    int c8  = (gid & 15) << 3;
    u32 outw[4];
    if (row < N_NODES) {
        const float4* p = (const float4*)(x + (size_t)row * DIM + c8);
        float4 v0 = p[0], v1 = p[1];
        outw[0] = (u32)f2bf(v0.x) | ((u32)f2bf(v0.y) << 16);
        outw[1] = (u32)f2bf(v0.z) | ((u32)f2bf(v0.w) << 16);
        outw[2] = (u32)f2bf(v1.x) | ((u32)f2bf(v1.y) << 16);
        outw[3] = (u32)f2bf(v1.z) | ((u32)f2bf(v1.w) << 16);
    } else {
        outw[0] = outw[1] = outw[2] = outw[3] = 0;
    }
    *(uint4*)(xb + (size_t)row * DIM + c8) = *(uint4*)outw;
}

// 6 weight matrices [128][128] f32 -> bf16, concatenated
__global__ void k_cast_w(const float* __restrict__ W1l, const float* __restrict__ W1r,
                         const float* __restrict__ W2l, const float* __restrict__ W2r,
                         const float* __restrict__ W3l, const float* __restrict__ W3r,
                         u16* __restrict__ out) {
    int i = blockIdx.x * 256 + threadIdx.x;   // 98304
    int mat = i >> 14, off = i & 16383;
    const float* src = (mat == 0) ? W1l : (mat == 1) ? W1r : (mat == 2) ? W2l
                     : (mat == 3) ? W2r : (mat == 4) ? W3l : W3r;
    out[i] = f2bf(src[off]);
}

// ---------------- mean aggregation (wave/node, bf16 in, bf16 out) ----------------

__global__ void k_aggregate(const u16* __restrict__ h, const int* __restrict__ csr_src,
                            const int* __restrict__ row_ptr, const int* __restrict__ deg,
                            const float* __restrict__ deg_inv, u16* __restrict__ agg) {
    int gid  = blockIdx.x * 256 + threadIdx.x;
    int node = gid >> 6;
    int lane = threadIdx.x & 63;
    if (node >= MPAD) return;
    size_t obase = (size_t)node * DIM + lane * 2;
    if (node >= N_NODES) { *(u32*)(agg + obase) = 0; return; }

    int start = row_ptr[node];
    int cnt   = deg[node];
    int l2    = lane * 2;
    float a0 = 0.f, a1 = 0.f;
    for (int c0 = 0; c0 < cnt; c0 += 64) {
        int rem = cnt - c0; if (rem > 64) rem = 64;
        int sidx = 0;
        if (lane < rem) sidx = csr_src[start + c0 + lane];
        int e = 0;
        for (; e + 4 <= rem; e += 4) {
            int s0 = __shfl(sidx, e);
            int s1 = __shfl(sidx, e + 1);
            int s2 = __shfl(sidx, e + 2);
            int s3 = __shfl(sidx, e + 3);
            u32 u0 = *(const u32*)(h + (size_t)s0 * DIM + l2);
            u32 u1 = *(const u32*)(h + (size_t)s1 * DIM + l2);
            u32 u2 = *(const u32*)(h + (size_t)s2 * DIM + l2);
            u32 u3 = *(const u32*)(h + (size_t)s3 * DIM + l2);
            a0 += bf2f((u16)(u0 & 0xffffu)) + bf2f((u16)(u1 & 0xffffu))
                + bf2f((u16)(u2 & 0xffffu)) + bf2f((u16)(u3 & 0xffffu));
            a1 += bf2f((u16)(u0 >> 16)) + bf2f((u16)(u1 >> 16))
                + bf2f((u16)(u2 >> 16)) + bf2f((u16)(u3 >> 16));
        }
        for (; e < rem; ++e) {
            int s = __shfl(sidx, e);
            u32 u = *(const u32*)(h + (size_t)s * DIM + l2);
            a0 += bf2f((u16)(u & 0xffffu));
            a1 += bf2f((u16)(u >> 16));
        }
    }
    float inv = deg_inv[node];
    a0 *= inv; a1 *= inv;
    *(u32*)(agg + obase) = (u32)f2bf(a0) | ((u32)f2bf(a1) << 16);
}

// ---------------- MFMA GEMM: out = act(agg@Wl^T + b + h@Wr^T) ----------------
// One wave per 16 rows. A-frag: lane holds A[m0+(l&15)][(l>>4)*8 .. +7].
// B-frag needs B[k][n] = W[n][k]: lane holds W[(nt*16+(l&15))][(l>>4)*8 .. +7]
// (row-major bf16 W, 16B/lane contiguous). D: col=l&15, row=(l>>4)*4+j.

template <bool RELU>
__global__ __launch_bounds__(256) void k_gemm_mfma(
    const u16* __restrict__ agg, const u16* __restrict__ h,
    const u16* __restrict__ Wl, const u16* __restrict__ Wr,
    const float* __restrict__ bias, u16* __restrict__ out) {
    const int lane = threadIdx.x & 63;
    const int wid  = threadIdx.x >> 6;
    const int m0   = (blockIdx.x * 4 + wid) * 16;
    const int fr   = lane & 15;
    const int kq   = (lane >> 4) << 3;

    bf16x8 aF[2][4];
    const u16* pa = agg + (size_t)(m0 + fr) * DIM + kq;
    const u16* ph = h   + (size_t)(m0 + fr) * DIM + kq;
#pragma unroll
    for (int kt = 0; kt < 4; ++kt) {
        aF[0][kt] = *(const bf16x8*)(pa + kt * 32);
        aF[1][kt] = *(const bf16x8*)(ph + kt * 32);
    }

    const int rbase = m0 + ((lane >> 4) << 2);
#pragma unroll
    for (int nt = 0; nt < 8; ++nt) {
        const u16* pwl = Wl + (size_t)(nt * 16 + fr) * DIM + kq;
        const u16* pwr = Wr + (size_t)(nt * 16 + fr) * DIM + kq;
        f32x4 acc = {0.f, 0.f, 0.f, 0.f};
#pragma unroll
        for (int kt = 0; kt < 4; ++kt) {
            bf16x8 w = *(const bf16x8*)(pwl + kt * 32);
            acc = __builtin_amdgcn_mfma_f32_16x16x32_bf16(aF[0][kt], w, acc, 0, 0, 0);
        }
#pragma unroll
        for (int kt = 0; kt < 4; ++kt) {
            bf16x8 w = *(const bf16x8*)(pwr + kt * 32);
            acc = __builtin_amdgcn_mfma_f32_16x16x32_bf16(aF[1][kt], w, acc, 0, 0, 0);
        }
        int col = nt * 16 + fr;
        float b = bias[col];
#pragma unroll
        for (int j = 0; j < 4; ++j) {
            float v = acc[j] + b;
            if (RELU) v = fmaxf(v, 0.f);
            out[(size_t)(rbase + j) * DIM + col] = f2bf(v);
        }
    }
}

// ---------------- head: softmax -> log_softmax -> NLL mean ----------------

__global__ void k_head(const u16* __restrict__ h3, const int* __restrict__ batch,
                       const int* __restrict__ labels, const float* __restrict__ Wlin,
                       const float* __restrict__ blin, float* __restrict__ accum) {
    int gid  = blockIdx.x * 256 + threadIdx.x;
    int wv   = gid >> 6;
    int lane = threadIdx.x & 63;
    float contrib = 0.f;
    if (wv < N_BATCH) {
        int n = batch[wv];
        u32 u = *(const u32*)(h3 + (size_t)n * DIM + lane * 2);
        float h0 = bf2f((u16)(u & 0xffffu));
        float h1 = bf2f((u16)(u >> 16));
        float w00 = Wlin[lane * 2],       w01 = Wlin[lane * 2 + 1];
        float w10 = Wlin[DIM + lane * 2], w11 = Wlin[DIM + lane * 2 + 1];
        float z0 = h0 * w00 + h1 * w01;
        float z1 = h0 * w10 + h1 * w11;
#pragma unroll
        for (int off = 32; off > 0; off >>= 1) {
            z0 += __shfl_xor(z0, off);
            z1 += __shfl_xor(z1, off);
        }
        z0 += blin[0]; z1 += blin[1];
        float m  = fmaxf(z0, z1);
        float e0 = expf(z0 - m), e1 = expf(z1 - m);
        float s  = e0 + e1;
        float p0 = e0 / s, p1 = e1 / s;
        float m2  = fmaxf(p0, p1);
        float lse = m2 + logf(expf(p0 - m2) + expf(p1 - m2));
        int lab = labels[n];
        float lp = ((lab == 0) ? p0 : p1) - lse;
        contrib = -lp * (1.0f / (float)N_BATCH);
    }
    __shared__ float sh[4];
    if (lane == 0) sh[threadIdx.x >> 6] = contrib;
    __syncthreads();
    if (threadIdx.x == 0) atomicAdd(accum, sh[0] + sh[1] + sh[2] + sh[3]);
}

__global__ void k_finalize(const float* accum, float* out) {
    if (threadIdx.x == 0) out[0] = accum[0];
}

// ---------------- launch ----------------

extern "C" void kernel_launch(void* const* d_in, const int* in_sizes, int n_in,
                              void* d_out, int out_size, void* d_ws, size_t ws_size,
                              hipStream_t stream) {
    const float* x    = (const float*)d_in[0];
    const int*   eidx = (const int*)d_in[1];
    const int*   batch  = (const int*)d_in[2];
    const int*   labels = (const int*)d_in[3];
    const float* W1l = (const float*)d_in[4];
    const float* b1  = (const float*)d_in[5];
    const float* W1r = (const float*)d_in[6];
    const float* W2l = (const float*)d_in[7];
    const float* b2  = (const float*)d_in[8];
    const float* W2r = (const float*)d_in[9];
    const float* W3l = (const float*)d_in[10];
    const float* b3  = (const float*)d_in[11];
    const float* W3r = (const float*)d_in[12];
    const float* Wlin = (const float*)d_in[13];
    const float* blin = (const float*)d_in[14];

    const int* src = eidx;
    const int* dst = eidx + N_EDGES;

    size_t off = 0;
    auto alloc = [&](size_t bytes) -> char* {
        off = (off + 511) & ~(size_t)511;
        char* p = (char*)d_ws + off;
        off += bytes;
        return p;
    };
    int*   deg     = (int*)  alloc(N_NODES * 4);
    int*   row_ptr = (int*)  alloc(N_NODES * 4);
    int*   cursor  = (int*)  alloc(N_NODES * 4);
    float* deg_inv = (float*)alloc(N_NODES * 4);
    int*   bsums   = (int*)  alloc(128 * 4);
    int*   boffs   = (int*)  alloc(128 * 4);
    int*   csr_src = (int*)  alloc(N_EDGES * 4);
    u16*   wb      = (u16*)  alloc(6 * DIM * DIM * 2);
    u16*   xb      = (u16*)  alloc((size_t)MPAD * DIM * 2);   // also reused as bufB
    u16*   agg     = (u16*)  alloc((size_t)MPAD * DIM * 2);
    u16*   bufA    = (u16*)  alloc((size_t)MPAD * DIM * 2);
    float* accum   = (float*)alloc(4);

    u16* bufB = xb;   // xb dead after layer-1 GEMM; reuse for layer-2 output

    u16* w1l = wb + 0 * DIM * DIM;
    u16* w1r = wb + 1 * DIM * DIM;
    u16* w2l = wb + 2 * DIM * DIM;
    u16* w2r = wb + 3 * DIM * DIM;
    u16* w3l = wb + 4 * DIM * DIM;
    u16* w3r = wb + 5 * DIM * DIM;

    const int ZB   = (N_NODES + 255) / 256;       // 196
    const int EB   = (N_EDGES + 255) / 256;       // 3125
    const int SB   = (N_NODES + 511) / 512;       // 98
    const int CXB  = MPAD * 16 / 256;             // 3128
    const int CWB  = 6 * DIM * DIM / 256;         // 384
    const int AGGB = MPAD * 64 / 256;             // 12512
    const int GB   = MPAD / 64;                   // 782
    const int HB   = N_BATCH * 64 / 256;          // 6250

    k_zero<<<ZB, 256, 0, stream>>>(deg, accum);
    k_hist<<<EB, 256, 0, stream>>>(dst, deg);
    k_block_sums<<<SB, 512, 0, stream>>>(deg, bsums);
    k_scan_bsums<<<1, 64, 0, stream>>>(bsums, boffs, SB);
    k_scan_final<<<SB, 512, 0, stream>>>(deg, boffs, row_ptr, cursor, deg_inv);
    k_scatter<<<EB, 256, 0, stream>>>(src, dst, cursor, csr_src);

    k_cast_x<<<CXB, 256, 0, stream>>>(x, xb);
    k_cast_w<<<CWB, 256, 0, stream>>>(W1l, W1r, W2l, W2r, W3l, W3r, wb);

    // layer 1: xb -> bufA
    k_aggregate<<<AGGB, 256, 0, stream>>>(xb, csr_src, row_ptr, deg, deg_inv, agg);
    k_gemm_mfma<true><<<GB, 256, 0, stream>>>(agg, xb, w1l, w1r, b1, bufA);
    // layer 2: bufA -> bufB (aliases xb)
    k_aggregate<<<AGGB, 256, 0, stream>>>(bufA, csr_src, row_ptr, deg, deg_inv, agg);
    k_gemm_mfma<true><<<GB, 256, 0, stream>>>(agg, bufA, w2l, w2r, b2, bufB);
    // layer 3: bufB -> bufA (h3)
    k_aggregate<<<AGGB, 256, 0, stream>>>(bufB, csr_src, row_ptr, deg, deg_inv, agg);
    k_gemm_mfma<false><<<GB, 256, 0, stream>>>(agg, bufB, w3l, w3r, b3, bufA);

    k_head<<<HB, 256, 0, stream>>>(bufA, batch, labels, Wlin, blin, accum);
    k_finalize<<<1, 64, 0, stream>>>(accum, (float*)d_out);
}

// Round 3
// 348.019 us; speedup vs baseline: 2.0698x; 1.1624x over previous
//
#include <hip/hip_runtime.h>
#include <hip/hip_bf16.h>

#define N_NODES 50000
#define MPAD    50048
#define N_EDGES 800000
#define DIM     128
#define N_BATCH 25000

typedef unsigned short u16;
typedef unsigned int   u32;

typedef __attribute__((ext_vector_type(8))) short bf16x8;
typedef __attribute__((ext_vector_type(4))) float f32x4;

static __device__ __forceinline__ float bf2f(u16 u) {
    union { u32 i; float f; } v; v.i = ((u32)u) << 16; return v.f;
}
static __device__ __forceinline__ u16 f2bf(float f) {
    union { float f; u32 i; } v; v.f = f;
    u32 x = v.i;
    u32 r = x + 0x7fffu + ((x >> 16) & 1u);   // RTNE
    return (u16)(r >> 16);
}

// ---------------- CSR build ----------------

__global__ void k_zero(int* deg, float* accum) {
    int i = blockIdx.x * 256 + threadIdx.x;
    if (i < N_NODES) deg[i] = 0;
    if (i == 0) accum[0] = 0.f;
}

__global__ void k_hist(const int* dst, int* deg) {
    int e = blockIdx.x * 256 + threadIdx.x;
    if (e < N_EDGES) atomicAdd(&deg[dst[e]], 1);
}

__global__ void k_block_sums(const int* deg, int* bsums) {
    __shared__ int sh[512];
    int i = blockIdx.x * 512 + threadIdx.x;
    sh[threadIdx.x] = (i < N_NODES) ? deg[i] : 0;
    __syncthreads();
    for (int off = 256; off > 0; off >>= 1) {
        if (threadIdx.x < off) sh[threadIdx.x] += sh[threadIdx.x + off];
        __syncthreads();
    }
    if (threadIdx.x == 0) bsums[blockIdx.x] = sh[0];
}

__global__ void k_scan_bsums(const int* bsums, int* boffs, int nb) {
    if (threadIdx.x == 0) {
        int run = 0;
        for (int i = 0; i < nb; ++i) { boffs[i] = run; run += bsums[i]; }
    }
}

__global__ void k_scan_final(const int* deg, const int* boffs,
                             int* row_ptr, int* cursor, float* deg_inv) {
    __shared__ int sh[512];
    int i = blockIdx.x * 512 + threadIdx.x;
    int v = (i < N_NODES) ? deg[i] : 0;
    sh[threadIdx.x] = v;
    __syncthreads();
    for (int off = 1; off < 512; off <<= 1) {
        int x = (threadIdx.x >= (unsigned)off) ? sh[threadIdx.x - off] : 0;
        __syncthreads();
        sh[threadIdx.x] += x;
        __syncthreads();
    }
    if (i < N_NODES) {
        int excl = sh[threadIdx.x] - v + boffs[blockIdx.x];
        row_ptr[i] = excl;
        cursor[i]  = excl;
        deg_inv[i] = 1.0f / (float)(v < 1 ? 1 : v);
    }
}

__global__ void k_scatter(const int* src, const int* dst, int* cursor, int* csr_src) {
    int e = blockIdx.x * 256 + threadIdx.x;
    if (e < N_EDGES) {
        int d = dst[e];
        int pos = atomicAdd(&cursor[d], 1);
        csr_src[pos] = src[e];
    }
}

// ---------------- casts ----------------

__global__ void k_cast_x(const float* __restrict__ x, u16* __restrict__ xb) {
    int gid = blockIdx.x * 256 + threadIdx.x;   // MPAD*16 threads, 8 elems each
    int row = gid >> 4;
    int c8  = (gid & 15) << 3;
    u32 outw[4];
    if (row < N_NODES) {
        const float4* p = (const float4*)(x + (size_t)row * DIM + c8);
        float4 v0 = p[0], v1 = p[1];
        outw[0] = (u32)f2bf(v0.x) | ((u32)f2bf(v0.y) << 16);
        outw[1] = (u32)f2bf(v0.z) | ((u32)f2bf(v0.w) << 16);
        outw[2] = (u32)f2bf(v1.x) | ((u32)f2bf(v1.y) << 16);
        outw[3] = (u32)f2bf(v1.z) | ((u32)f2bf(v1.w) << 16);
    } else {
        outw[0] = outw[1] = outw[2] = outw[3] = 0;
    }
    *(uint4*)(xb + (size_t)row * DIM + c8) = *(uint4*)outw;
}

__global__ void k_cast_w(const float* __restrict__ W1l, const float* __restrict__ W1r,
                         const float* __restrict__ W2l, const float* __restrict__ W2r,
                         const float* __restrict__ W3l, const float* __restrict__ W3r,
                         u16* __restrict__ out) {
    int i = blockIdx.x * 256 + threadIdx.x;   // 98304
    int mat = i >> 14, off = i & 16383;
    const float* src = (mat == 0) ? W1l : (mat == 1) ? W1r : (mat == 2) ? W2l
                     : (mat == 3) ? W2r : (mat == 4) ? W3l : W3r;
    out[i] = f2bf(src[off]);
}

// ---------------- mean aggregation (wave/node, bf16 in, bf16 out) ----------------

__global__ void k_aggregate(const u16* __restrict__ h, const int* __restrict__ csr_src,
                            const int* __restrict__ row_ptr, const int* __restrict__ deg,
                            const float* __restrict__ deg_inv, u16* __restrict__ agg) {
    int gid  = blockIdx.x * 256 + threadIdx.x;
    int node = gid >> 6;
    int lane = threadIdx.x & 63;
    if (node >= MPAD) return;
    size_t obase = (size_t)node * DIM + lane * 2;
    if (node >= N_NODES) { *(u32*)(agg + obase) = 0; return; }

    int start = row_ptr[node];
    int cnt   = deg[node];
    int l2    = lane * 2;
    float a0 = 0.f, a1 = 0.f;
    for (int c0 = 0; c0 < cnt; c0 += 64) {
        int rem = cnt - c0; if (rem > 64) rem = 64;
        int sidx = 0;
        if (lane < rem) sidx = csr_src[start + c0 + lane];
        int e = 0;
        for (; e + 8 <= rem; e += 8) {
            u32 u0 = *(const u32*)(h + (size_t)__shfl(sidx, e)     * DIM + l2);
            u32 u1 = *(const u32*)(h + (size_t)__shfl(sidx, e + 1) * DIM + l2);
            u32 u2 = *(const u32*)(h + (size_t)__shfl(sidx, e + 2) * DIM + l2);
            u32 u3 = *(const u32*)(h + (size_t)__shfl(sidx, e + 3) * DIM + l2);
            u32 u4 = *(const u32*)(h + (size_t)__shfl(sidx, e + 4) * DIM + l2);
            u32 u5 = *(const u32*)(h + (size_t)__shfl(sidx, e + 5) * DIM + l2);
            u32 u6 = *(const u32*)(h + (size_t)__shfl(sidx, e + 6) * DIM + l2);
            u32 u7 = *(const u32*)(h + (size_t)__shfl(sidx, e + 7) * DIM + l2);
            a0 += bf2f((u16)(u0 & 0xffffu)) + bf2f((u16)(u1 & 0xffffu))
                + bf2f((u16)(u2 & 0xffffu)) + bf2f((u16)(u3 & 0xffffu))
                + bf2f((u16)(u4 & 0xffffu)) + bf2f((u16)(u5 & 0xffffu))
                + bf2f((u16)(u6 & 0xffffu)) + bf2f((u16)(u7 & 0xffffu));
            a1 += bf2f((u16)(u0 >> 16)) + bf2f((u16)(u1 >> 16))
                + bf2f((u16)(u2 >> 16)) + bf2f((u16)(u3 >> 16))
                + bf2f((u16)(u4 >> 16)) + bf2f((u16)(u5 >> 16))
                + bf2f((u16)(u6 >> 16)) + bf2f((u16)(u7 >> 16));
        }
        for (; e < rem; ++e) {
            int s = __shfl(sidx, e);
            u32 u = *(const u32*)(h + (size_t)s * DIM + l2);
            a0 += bf2f((u16)(u & 0xffffu));
            a1 += bf2f((u16)(u >> 16));
        }
    }
    float inv = deg_inv[node];
    a0 *= inv; a1 *= inv;
    *(u32*)(agg + obase) = (u32)f2bf(a0) | ((u32)f2bf(a1) << 16);
}

// ---------------- MFMA GEMM: out = act(agg@Wl^T + b + h@Wr^T) ----------------

template <bool RELU>
__global__ __launch_bounds__(256) void k_gemm_mfma(
    const u16* __restrict__ agg, const u16* __restrict__ h,
    const u16* __restrict__ Wl, const u16* __restrict__ Wr,
    const float* __restrict__ bias, u16* __restrict__ out) {
    const int lane = threadIdx.x & 63;
    const int wid  = threadIdx.x >> 6;
    const int m0   = (blockIdx.x * 4 + wid) * 16;
    const int fr   = lane & 15;
    const int kq   = (lane >> 4) << 3;

    bf16x8 aF[2][4];
    const u16* pa = agg + (size_t)(m0 + fr) * DIM + kq;
    const u16* ph = h   + (size_t)(m0 + fr) * DIM + kq;
#pragma unroll
    for (int kt = 0; kt < 4; ++kt) {
        aF[0][kt] = *(const bf16x8*)(pa + kt * 32);
        aF[1][kt] = *(const bf16x8*)(ph + kt * 32);
    }

    const int rbase = m0 + ((lane >> 4) << 2);
#pragma unroll
    for (int nt = 0; nt < 8; ++nt) {
        const u16* pwl = Wl + (size_t)(nt * 16 + fr) * DIM + kq;
        const u16* pwr = Wr + (size_t)(nt * 16 + fr) * DIM + kq;
        f32x4 acc = {0.f, 0.f, 0.f, 0.f};
#pragma unroll
        for (int kt = 0; kt < 4; ++kt) {
            bf16x8 w = *(const bf16x8*)(pwl + kt * 32);
            acc = __builtin_amdgcn_mfma_f32_16x16x32_bf16(aF[0][kt], w, acc, 0, 0, 0);
        }
#pragma unroll
        for (int kt = 0; kt < 4; ++kt) {
            bf16x8 w = *(const bf16x8*)(pwr + kt * 32);
            acc = __builtin_amdgcn_mfma_f32_16x16x32_bf16(aF[1][kt], w, acc, 0, 0, 0);
        }
        int col = nt * 16 + fr;
        float b = bias[col];
#pragma unroll
        for (int j = 0; j < 4; ++j) {
            float v = acc[j] + b;
            if (RELU) v = fmaxf(v, 0.f);
            out[(size_t)(rbase + j) * DIM + col] = f2bf(v);
        }
    }
}

// ---------------- head: 16 lanes per sample, 4 samples/wave ----------------
// lane group g = lane>>4 handles sample wv*4+g; lane l reads 16B (8 bf16) at
// col ((l&15)*8); dot with Wlin staged in LDS; xor-reduce over 16 lanes.

__global__ __launch_bounds__(256) void k_head(
    const u16* __restrict__ h3, const int* __restrict__ batch,
    const int* __restrict__ labels, const float* __restrict__ Wlin,
    const float* __restrict__ blin, float* __restrict__ accum) {
    __shared__ float wsh[256];
    __shared__ float red[4];
    int t = threadIdx.x;
    wsh[t] = Wlin[t];                 // [0..127]=row0, [128..255]=row1
    __syncthreads();

    int lane = t & 63;
    int g    = lane >> 4;             // sample group in wave
    int sub  = lane & 15;             // 16B chunk within row
    int wv   = (blockIdx.x * 256 + t) >> 6;
    int samp = wv * 4 + g;

    float contrib = 0.f;
    float z0 = 0.f, z1 = 0.f;
    int n = 0;
    if (samp < N_BATCH) {
        n = batch[samp];
        uint4 u = *(const uint4*)(h3 + (size_t)n * DIM + sub * 8);
        const u32* uw = (const u32*)&u;
        int cb = sub * 8;
#pragma unroll
        for (int q = 0; q < 4; ++q) {
            float hlo = bf2f((u16)(uw[q] & 0xffffu));
            float hhi = bf2f((u16)(uw[q] >> 16));
            z0 += hlo * wsh[cb + q * 2]     + hhi * wsh[cb + q * 2 + 1];
            z1 += hlo * wsh[128 + cb + q * 2] + hhi * wsh[128 + cb + q * 2 + 1];
        }
    }
#pragma unroll
    for (int off = 8; off > 0; off >>= 1) {
        z0 += __shfl_xor(z0, off);
        z1 += __shfl_xor(z1, off);
    }
    if (samp < N_BATCH) {
        z0 += blin[0]; z1 += blin[1];
        float m  = fmaxf(z0, z1);
        float e0 = expf(z0 - m), e1 = expf(z1 - m);
        float s  = e0 + e1;
        float p0 = e0 / s, p1 = e1 / s;
        float m2  = fmaxf(p0, p1);
        float lse = m2 + logf(expf(p0 - m2) + expf(p1 - m2));
        int lab = labels[n];
        float lp = ((lab == 0) ? p0 : p1) - lse;
        if (sub == 0) contrib = -lp * (1.0f / (float)N_BATCH);
    }
    // wave reduce (only sub==0 lanes hold nonzero)
#pragma unroll
    for (int off = 16; off < 64; off <<= 1) contrib += __shfl_xor(contrib, off);
    if (lane == 0) red[t >> 6] = contrib;
    __syncthreads();
    if (t == 0) atomicAdd(accum, red[0] + red[1] + red[2] + red[3]);
}

__global__ void k_finalize(const float* accum, float* out) {
    if (threadIdx.x == 0) out[0] = accum[0];
}

// ---------------- launch ----------------

extern "C" void kernel_launch(void* const* d_in, const int* in_sizes, int n_in,
                              void* d_out, int out_size, void* d_ws, size_t ws_size,
                              hipStream_t stream) {
    const float* x    = (const float*)d_in[0];
    const int*   eidx = (const int*)d_in[1];
    const int*   batch  = (const int*)d_in[2];
    const int*   labels = (const int*)d_in[3];
    const float* W1l = (const float*)d_in[4];
    const float* b1  = (const float*)d_in[5];
    const float* W1r = (const float*)d_in[6];
    const float* W2l = (const float*)d_in[7];
    const float* b2  = (const float*)d_in[8];
    const float* W2r = (const float*)d_in[9];
    const float* W3l = (const float*)d_in[10];
    const float* b3  = (const float*)d_in[11];
    const float* W3r = (const float*)d_in[12];
    const float* Wlin = (const float*)d_in[13];
    const float* blin = (const float*)d_in[14];

    const int* src = eidx;
    const int* dst = eidx + N_EDGES;

    size_t off = 0;
    auto alloc = [&](size_t bytes) -> char* {
        off = (off + 511) & ~(size_t)511;
        char* p = (char*)d_ws + off;
        off += bytes;
        return p;
    };
    int*   deg     = (int*)  alloc(N_NODES * 4);
    int*   row_ptr = (int*)  alloc(N_NODES * 4);
    int*   cursor  = (int*)  alloc(N_NODES * 4);
    float* deg_inv = (float*)alloc(N_NODES * 4);
    int*   bsums   = (int*)  alloc(128 * 4);
    int*   boffs   = (int*)  alloc(128 * 4);
    int*   csr_src = (int*)  alloc(N_EDGES * 4);
    u16*   wb      = (u16*)  alloc(6 * DIM * DIM * 2);
    u16*   xb      = (u16*)  alloc((size_t)MPAD * DIM * 2);   // reused as bufB
    u16*   agg     = (u16*)  alloc((size_t)MPAD * DIM * 2);
    u16*   bufA    = (u16*)  alloc((size_t)MPAD * DIM * 2);
    float* accum   = (float*)alloc(4);

    u16* bufB = xb;

    u16* w1l = wb + 0 * DIM * DIM;
    u16* w1r = wb + 1 * DIM * DIM;
    u16* w2l = wb + 2 * DIM * DIM;
    u16* w2r = wb + 3 * DIM * DIM;
    u16* w3l = wb + 4 * DIM * DIM;
    u16* w3r = wb + 5 * DIM * DIM;

    const int ZB   = (N_NODES + 255) / 256;       // 196
    const int EB   = (N_EDGES + 255) / 256;       // 3125
    const int SB   = (N_NODES + 511) / 512;       // 98
    const int CXB  = MPAD * 16 / 256;             // 3128
    const int CWB  = 6 * DIM * DIM / 256;         // 384
    const int AGGB = MPAD * 64 / 256;             // 12512
    const int GB   = MPAD / 64;                   // 782
    const int HB   = (N_BATCH / 4 + 3) / 4 + ((N_BATCH % 16) ? 1 : 0); // computed below

    k_zero<<<ZB, 256, 0, stream>>>(deg, accum);
    k_hist<<<EB, 256, 0, stream>>>(dst, deg);
    k_block_sums<<<SB, 512, 0, stream>>>(deg, bsums);
    k_scan_bsums<<<1, 64, 0, stream>>>(bsums, boffs, SB);
    k_scan_final<<<SB, 512, 0, stream>>>(deg, boffs, row_ptr, cursor, deg_inv);
    k_scatter<<<EB, 256, 0, stream>>>(src, dst, cursor, csr_src);

    k_cast_x<<<CXB, 256, 0, stream>>>(x, xb);
    k_cast_w<<<CWB, 256, 0, stream>>>(W1l, W1r, W2l, W2r, W3l, W3r, wb);

    k_aggregate<<<AGGB, 256, 0, stream>>>(xb, csr_src, row_ptr, deg, deg_inv, agg);
    k_gemm_mfma<true><<<GB, 256, 0, stream>>>(agg, xb, w1l, w1r, b1, bufA);
    k_aggregate<<<AGGB, 256, 0, stream>>>(bufA, csr_src, row_ptr, deg, deg_inv, agg);
    k_gemm_mfma<true><<<GB, 256, 0, stream>>>(agg, bufA, w2l, w2r, b2, bufB);
    k_aggregate<<<AGGB, 256, 0, stream>>>(bufB, csr_src, row_ptr, deg, deg_inv, agg);
    k_gemm_mfma<false><<<GB, 256, 0, stream>>>(agg, bufB, w3l, w3r, b3, bufA);

    // 16 samples per wave-group? 4 samples/wave, 4 waves/block = 16 samples/block
    {
        const int HB2 = (N_BATCH + 15) / 16;      // 1563
        k_head<<<HB2, 256, 0, stream>>>(bufA, batch, labels, Wlin, blin, accum);
    }
    k_finalize<<<1, 64, 0, stream>>>(accum, (float*)d_out);
}

// Round 4
// 309.804 us; speedup vs baseline: 2.3252x; 1.1234x over previous
//
#include <hip/hip_runtime.h>
#include <hip/hip_bf16.h>

#define N_NODES 50000
#define MPAD    50048
#define N_EDGES 800000
#define DIM     128
#define N_BATCH 25000
#define NBUCK   196        // ceil(50000/256) buckets of 256 dst nodes

typedef unsigned short u16;
typedef unsigned int   u32;
typedef unsigned long long u64;

typedef __attribute__((ext_vector_type(8))) short bf16x8;
typedef __attribute__((ext_vector_type(4))) float f32x4;

static __device__ __forceinline__ float bf2f(u16 u) {
    union { u32 i; float f; } v; v.i = ((u32)u) << 16; return v.f;
}
static __device__ __forceinline__ u16 f2bf(float f) {
    union { float f; u32 i; } v; v.f = f;
    u32 x = v.i;
    u32 r = x + 0x7fffu + ((x >> 16) & 1u);   // RTNE
    return (u16)(r >> 16);
}

// ---------------- CSR build ----------------

__global__ void k_zero(int* deg, float* accum) {
    int i = blockIdx.x * 256 + threadIdx.x;
    if (i < N_NODES) deg[i] = 0;
    if (i == 0) accum[0] = 0.f;
}

__global__ void k_hist(const int* dst, int* deg) {
    int e = blockIdx.x * 256 + threadIdx.x;
    if (e < N_EDGES) atomicAdd(&deg[dst[e]], 1);
}

__global__ void k_block_sums(const int* deg, int* bsums) {
    __shared__ int sh[512];
    int i = blockIdx.x * 512 + threadIdx.x;
    sh[threadIdx.x] = (i < N_NODES) ? deg[i] : 0;
    __syncthreads();
    for (int off = 256; off > 0; off >>= 1) {
        if (threadIdx.x < off) sh[threadIdx.x] += sh[threadIdx.x + off];
        __syncthreads();
    }
    if (threadIdx.x == 0) bsums[blockIdx.x] = sh[0];
}

__global__ void k_scan_bsums(const int* bsums, int* boffs, int nb) {
    if (threadIdx.x == 0) {
        int run = 0;
        for (int i = 0; i < nb; ++i) { boffs[i] = run; run += bsums[i]; }
    }
}

// also emits bucket cursors bcur[b] = row_ptr[256*b]
__global__ void k_scan_final(const int* deg, const int* boffs,
                             int* row_ptr, int* bcur, float* deg_inv) {
    __shared__ int sh[512];
    int i = blockIdx.x * 512 + threadIdx.x;
    int v = (i < N_NODES) ? deg[i] : 0;
    sh[threadIdx.x] = v;
    __syncthreads();
    for (int off = 1; off < 512; off <<= 1) {
        int x = (threadIdx.x >= (unsigned)off) ? sh[threadIdx.x - off] : 0;
        __syncthreads();
        sh[threadIdx.x] += x;
        __syncthreads();
    }
    if (i < N_NODES) {
        int excl = sh[threadIdx.x] - v + boffs[blockIdx.x];
        row_ptr[i] = excl;
        if ((i & 255) == 0) bcur[i >> 8] = excl;
        deg_inv[i] = 1.0f / (float)(v < 1 ? 1 : v);
    }
}

// ---- phase 1: partition edges into 196 dst-buckets, LDS-staged coalesced ----

__global__ __launch_bounds__(256) void k_part(const int* __restrict__ src,
                                              const int* __restrict__ dst,
                                              int* __restrict__ bcur,
                                              u64* __restrict__ ebuf) {
    __shared__ int hist[NBUCK];
    __shared__ int lbase[NBUCK];
    __shared__ int gdelta[NBUCK];
    __shared__ u64 stage[4096];
    __shared__ int gaddr[4096];
    int t = threadIdx.x;
    for (int i = t; i < NBUCK; i += 256) hist[i] = 0;
    __syncthreads();

    int base = blockIdx.x * 4096;
    int cnt = N_EDGES - base; if (cnt > 4096) cnt = 4096; if (cnt < 0) cnt = 0;

    int es[16], ed[16], rr[16];
#pragma unroll
    for (int k = 0; k < 16; ++k) {
        int i = t + (k << 8);
        bool ok = i < cnt;
        int e = ok ? (base + i) : 0;
        int s = src[e], d = dst[e];
        es[k] = s; ed[k] = d;
        int r = -1;
        if (ok) r = atomicAdd(&hist[d >> 8], 1);
        rr[k] = r;
    }
    __syncthreads();

    // exclusive scan of hist[196] by wave 0
    if (t < 64) {
        int run = 0;
        for (int c = 0; c < 4; ++c) {
            int idx = c * 64 + t;
            int v = (idx < NBUCK) ? hist[idx] : 0;
            int orig = v;
            for (int off = 1; off < 64; off <<= 1) {
                int u = __shfl_up(v, off);
                if (t >= off) v += u;
            }
            int tot = __shfl(v, 63);
            if (idx < NBUCK) lbase[idx] = run + v - orig;
            run += tot;
        }
    }
    __syncthreads();

    if (t < NBUCK) {
        int c = hist[t];
        int g = atomicAdd(&bcur[t], c);
        gdelta[t] = g - lbase[t];
    }
    __syncthreads();

#pragma unroll
    for (int k = 0; k < 16; ++k) {
        if (rr[k] >= 0) {
            int b = ed[k] >> 8;
            int slot = lbase[b] + rr[k];
            stage[slot] = (((u64)(u32)ed[k]) << 32) | (u32)es[k];
            gaddr[slot] = gdelta[b] + slot;
        }
    }
    __syncthreads();

    for (int i = t; i < cnt; i += 256) {
        ebuf[gaddr[i]] = stage[i];
    }
}

// ---- phase 2: per-bucket scatter into block-private contiguous csr region ----

__global__ __launch_bounds__(256) void k_scatter2(const u64* __restrict__ ebuf,
                                                  const int* __restrict__ row_ptr,
                                                  int* __restrict__ csr_src) {
    __shared__ int cur[256];
    int b  = blockIdx.x;
    int n0 = b << 8;
    int t  = threadIdx.x;
    int n  = n0 + t;
    if (n < N_NODES) cur[t] = row_ptr[n];
    __syncthreads();
    int start = row_ptr[n0];
    int end   = (n0 + 256 < N_NODES) ? row_ptr[n0 + 256] : N_EDGES;
    for (int e = start + t; e < end; e += 256) {
        u64 p = ebuf[e];
        int s = (int)(u32)(p & 0xffffffffULL);
        int d = (int)(u32)(p >> 32);
        int pos = atomicAdd(&cur[d - n0], 1);
        csr_src[pos] = s;
    }
}

// ---------------- casts ----------------

__global__ void k_cast_x(const float* __restrict__ x, u16* __restrict__ xb) {
    int gid = blockIdx.x * 256 + threadIdx.x;
    int row = gid >> 4;
    int c8  = (gid & 15) << 3;
    u32 outw[4];
    if (row < N_NODES) {
        const float4* p = (const float4*)(x + (size_t)row * DIM + c8);
        float4 v0 = p[0], v1 = p[1];
        outw[0] = (u32)f2bf(v0.x) | ((u32)f2bf(v0.y) << 16);
        outw[1] = (u32)f2bf(v0.z) | ((u32)f2bf(v0.w) << 16);
        outw[2] = (u32)f2bf(v1.x) | ((u32)f2bf(v1.y) << 16);
        outw[3] = (u32)f2bf(v1.z) | ((u32)f2bf(v1.w) << 16);
    } else {
        outw[0] = outw[1] = outw[2] = outw[3] = 0;
    }
    *(uint4*)(xb + (size_t)row * DIM + c8) = *(uint4*)outw;
}

__global__ void k_cast_w(const float* __restrict__ W1l, const float* __restrict__ W1r,
                         const float* __restrict__ W2l, const float* __restrict__ W2r,
                         const float* __restrict__ W3l, const float* __restrict__ W3r,
                         u16* __restrict__ out) {
    int i = blockIdx.x * 256 + threadIdx.x;
    int mat = i >> 14, off = i & 16383;
    const float* src = (mat == 0) ? W1l : (mat == 1) ? W1r : (mat == 2) ? W2l
                     : (mat == 3) ? W2r : (mat == 4) ? W3l : W3r;
    out[i] = f2bf(src[off]);
}

// ------- mean aggregation: 16 lanes/node, 4 nodes/wave, uint4 gathers -------

__global__ __launch_bounds__(256) void k_aggregate(
    const u16* __restrict__ h, const int* __restrict__ csr_src,
    const int* __restrict__ row_ptr, const int* __restrict__ deg,
    const float* __restrict__ deg_inv, u16* __restrict__ agg) {
    int t    = threadIdx.x;
    int lane = t & 63;
    int sub  = lane & 15;
    int node = blockIdx.x * 16 + ((t >> 6) << 2) + (lane >> 4);
    size_t obase = (size_t)node * DIM + sub * 8;
    if (node >= N_NODES) {
        if (node < MPAD) { uint4 z = {0, 0, 0, 0}; *(uint4*)(agg + obase) = z; }
        return;
    }
    int start = row_ptr[node];
    int cnt   = deg[node];
    int gb    = lane & 48;
    float a0 = 0, a1 = 0, a2 = 0, a3 = 0, a4 = 0, a5 = 0, a6 = 0, a7 = 0;

#define ACC(u) { a0 += bf2f((u16)((u).x & 0xffffu)); a1 += bf2f((u16)((u).x >> 16)); \
                 a2 += bf2f((u16)((u).y & 0xffffu)); a3 += bf2f((u16)((u).y >> 16)); \
                 a4 += bf2f((u16)((u).z & 0xffffu)); a5 += bf2f((u16)((u).z >> 16)); \
                 a6 += bf2f((u16)((u).w & 0xffffu)); a7 += bf2f((u16)((u).w >> 16)); }

    for (int c0 = 0; c0 < cnt; c0 += 16) {
        int rem = cnt - c0; if (rem > 16) rem = 16;
        int sidx = 0;
        if (sub < rem) sidx = csr_src[start + c0 + sub];
        int j = 0;
        for (; j + 4 <= rem; j += 4) {
            int i0 = __shfl(sidx, gb + j);
            int i1 = __shfl(sidx, gb + j + 1);
            int i2 = __shfl(sidx, gb + j + 2);
            int i3 = __shfl(sidx, gb + j + 3);
            uint4 r0 = *(const uint4*)(h + (size_t)i0 * DIM + sub * 8);
            uint4 r1 = *(const uint4*)(h + (size_t)i1 * DIM + sub * 8);
            uint4 r2 = *(const uint4*)(h + (size_t)i2 * DIM + sub * 8);
            uint4 r3 = *(const uint4*)(h + (size_t)i3 * DIM + sub * 8);
            ACC(r0); ACC(r1); ACC(r2); ACC(r3);
        }
        for (; j < rem; ++j) {
            int i0 = __shfl(sidx, gb + j);
            uint4 r0 = *(const uint4*)(h + (size_t)i0 * DIM + sub * 8);
            ACC(r0);
        }
    }
#undef ACC
    float inv = deg_inv[node];
    a0 *= inv; a1 *= inv; a2 *= inv; a3 *= inv;
    a4 *= inv; a5 *= inv; a6 *= inv; a7 *= inv;
    uint4 o;
    o.x = (u32)f2bf(a0) | ((u32)f2bf(a1) << 16);
    o.y = (u32)f2bf(a2) | ((u32)f2bf(a3) << 16);
    o.z = (u32)f2bf(a4) | ((u32)f2bf(a5) << 16);
    o.w = (u32)f2bf(a6) | ((u32)f2bf(a7) << 16);
    *(uint4*)(agg + obase) = o;
}

// ---------------- MFMA GEMM: out = act(agg@Wl^T + b + h@Wr^T) ----------------

template <bool RELU>
__global__ __launch_bounds__(256) void k_gemm_mfma(
    const u16* __restrict__ agg, const u16* __restrict__ h,
    const u16* __restrict__ Wl, const u16* __restrict__ Wr,
    const float* __restrict__ bias, u16* __restrict__ out) {
    const int lane = threadIdx.x & 63;
    const int wid  = threadIdx.x >> 6;
    const int m0   = (blockIdx.x * 4 + wid) * 16;
    const int fr   = lane & 15;
    const int kq   = (lane >> 4) << 3;

    bf16x8 aF[2][4];
    const u16* pa = agg + (size_t)(m0 + fr) * DIM + kq;
    const u16* ph = h   + (size_t)(m0 + fr) * DIM + kq;
#pragma unroll
    for (int kt = 0; kt < 4; ++kt) {
        aF[0][kt] = *(const bf16x8*)(pa + kt * 32);
        aF[1][kt] = *(const bf16x8*)(ph + kt * 32);
    }

    const int rbase = m0 + ((lane >> 4) << 2);
#pragma unroll
    for (int nt = 0; nt < 8; ++nt) {
        const u16* pwl = Wl + (size_t)(nt * 16 + fr) * DIM + kq;
        const u16* pwr = Wr + (size_t)(nt * 16 + fr) * DIM + kq;
        f32x4 acc = {0.f, 0.f, 0.f, 0.f};
#pragma unroll
        for (int kt = 0; kt < 4; ++kt) {
            bf16x8 w = *(const bf16x8*)(pwl + kt * 32);
            acc = __builtin_amdgcn_mfma_f32_16x16x32_bf16(aF[0][kt], w, acc, 0, 0, 0);
        }
#pragma unroll
        for (int kt = 0; kt < 4; ++kt) {
            bf16x8 w = *(const bf16x8*)(pwr + kt * 32);
            acc = __builtin_amdgcn_mfma_f32_16x16x32_bf16(aF[1][kt], w, acc, 0, 0, 0);
        }
        int col = nt * 16 + fr;
        float b = bias[col];
#pragma unroll
        for (int j = 0; j < 4; ++j) {
            float v = acc[j] + b;
            if (RELU) v = fmaxf(v, 0.f);
            out[(size_t)(rbase + j) * DIM + col] = f2bf(v);
        }
    }
}

// ---------------- head: 16 lanes per sample, 4 samples/wave ----------------

__global__ __launch_bounds__(256) void k_head(
    const u16* __restrict__ h3, const int* __restrict__ batch,
    const int* __restrict__ labels, const float* __restrict__ Wlin,
    const float* __restrict__ blin, float* __restrict__ accum) {
    __shared__ float wsh[256];
    __shared__ float red[4];
    int t = threadIdx.x;
    wsh[t] = Wlin[t];
    __syncthreads();

    int lane = t & 63;
    int g    = lane >> 4;
    int sub  = lane & 15;
    int wv   = (blockIdx.x * 256 + t) >> 6;
    int samp = wv * 4 + g;

    float contrib = 0.f;
    float z0 = 0.f, z1 = 0.f;
    int n = 0;
    if (samp < N_BATCH) {
        n = batch[samp];
        uint4 u = *(const uint4*)(h3 + (size_t)n * DIM + sub * 8);
        const u32* uw = (const u32*)&u;
        int cb = sub * 8;
#pragma unroll
        for (int q = 0; q < 4; ++q) {
            float hlo = bf2f((u16)(uw[q] & 0xffffu));
            float hhi = bf2f((u16)(uw[q] >> 16));
            z0 += hlo * wsh[cb + q * 2]       + hhi * wsh[cb + q * 2 + 1];
            z1 += hlo * wsh[128 + cb + q * 2] + hhi * wsh[128 + cb + q * 2 + 1];
        }
    }
#pragma unroll
    for (int off = 8; off > 0; off >>= 1) {
        z0 += __shfl_xor(z0, off);
        z1 += __shfl_xor(z1, off);
    }
    if (samp < N_BATCH) {
        z0 += blin[0]; z1 += blin[1];
        float m  = fmaxf(z0, z1);
        float e0 = expf(z0 - m), e1 = expf(z1 - m);
        float s  = e0 + e1;
        float p0 = e0 / s, p1 = e1 / s;
        float m2  = fmaxf(p0, p1);
        float lse = m2 + logf(expf(p0 - m2) + expf(p1 - m2));
        int lab = labels[n];
        float lp = ((lab == 0) ? p0 : p1) - lse;
        if (sub == 0) contrib = -lp * (1.0f / (float)N_BATCH);
    }
#pragma unroll
    for (int off = 16; off < 64; off <<= 1) contrib += __shfl_xor(contrib, off);
    if (lane == 0) red[t >> 6] = contrib;
    __syncthreads();
    if (t == 0) atomicAdd(accum, red[0] + red[1] + red[2] + red[3]);
}

__global__ void k_finalize(const float* accum, float* out) {
    if (threadIdx.x == 0) out[0] = accum[0];
}

// ---------------- launch ----------------

extern "C" void kernel_launch(void* const* d_in, const int* in_sizes, int n_in,
                              void* d_out, int out_size, void* d_ws, size_t ws_size,
                              hipStream_t stream) {
    const float* x    = (const float*)d_in[0];
    const int*   eidx = (const int*)d_in[1];
    const int*   batch  = (const int*)d_in[2];
    const int*   labels = (const int*)d_in[3];
    const float* W1l = (const float*)d_in[4];
    const float* b1  = (const float*)d_in[5];
    const float* W1r = (const float*)d_in[6];
    const float* W2l = (const float*)d_in[7];
    const float* b2  = (const float*)d_in[8];
    const float* W2r = (const float*)d_in[9];
    const float* W3l = (const float*)d_in[10];
    const float* b3  = (const float*)d_in[11];
    const float* W3r = (const float*)d_in[12];
    const float* Wlin = (const float*)d_in[13];
    const float* blin = (const float*)d_in[14];

    const int* src = eidx;
    const int* dst = eidx + N_EDGES;

    size_t off = 0;
    auto alloc = [&](size_t bytes) -> char* {
        off = (off + 511) & ~(size_t)511;
        char* p = (char*)d_ws + off;
        off += bytes;
        return p;
    };
    int*   deg     = (int*)  alloc(N_NODES * 4);
    int*   row_ptr = (int*)  alloc(N_NODES * 4);
    float* deg_inv = (float*)alloc(N_NODES * 4);
    int*   bsums   = (int*)  alloc(128 * 4);
    int*   boffs   = (int*)  alloc(128 * 4);
    int*   bcur    = (int*)  alloc(NBUCK * 4);
    int*   csr_src = (int*)  alloc(N_EDGES * 4);
    u64*   ebuf    = (u64*)  alloc((size_t)N_EDGES * 8);
    u16*   wb      = (u16*)  alloc(6 * DIM * DIM * 2);
    u16*   xb      = (u16*)  alloc((size_t)MPAD * DIM * 2);   // reused as bufB
    u16*   agg     = (u16*)  alloc((size_t)MPAD * DIM * 2);
    u16*   bufA    = (u16*)  alloc((size_t)MPAD * DIM * 2);
    float* accum   = (float*)alloc(4);

    u16* bufB = xb;

    u16* w1l = wb + 0 * DIM * DIM;
    u16* w1r = wb + 1 * DIM * DIM;
    u16* w2l = wb + 2 * DIM * DIM;
    u16* w2r = wb + 3 * DIM * DIM;
    u16* w3l = wb + 4 * DIM * DIM;
    u16* w3r = wb + 5 * DIM * DIM;

    const int ZB   = (N_NODES + 255) / 256;       // 196
    const int EB   = (N_EDGES + 255) / 256;       // 3125
    const int SB   = (N_NODES + 511) / 512;       // 98
    const int PB   = (N_EDGES + 4095) / 4096;     // 196
    const int CXB  = MPAD * 16 / 256;             // 3128
    const int CWB  = 6 * DIM * DIM / 256;         // 384
    const int AGGB = MPAD / 16;                   // 3128
    const int GB   = MPAD / 64;                   // 782
    const int HB2  = (N_BATCH + 15) / 16;         // 1563

    k_zero<<<ZB, 256, 0, stream>>>(deg, accum);
    k_hist<<<EB, 256, 0, stream>>>(dst, deg);
    k_block_sums<<<SB, 512, 0, stream>>>(deg, bsums);
    k_scan_bsums<<<1, 64, 0, stream>>>(bsums, boffs, SB);
    k_scan_final<<<SB, 512, 0, stream>>>(deg, boffs, row_ptr, bcur, deg_inv);
    k_part<<<PB, 256, 0, stream>>>(src, dst, bcur, ebuf);
    k_scatter2<<<NBUCK, 256, 0, stream>>>(ebuf, row_ptr, csr_src);

    k_cast_x<<<CXB, 256, 0, stream>>>(x, xb);
    k_cast_w<<<CWB, 256, 0, stream>>>(W1l, W1r, W2l, W2r, W3l, W3r, wb);

    k_aggregate<<<AGGB, 256, 0, stream>>>(xb, csr_src, row_ptr, deg, deg_inv, agg);
    k_gemm_mfma<true><<<GB, 256, 0, stream>>>(agg, xb, w1l, w1r, b1, bufA);
    k_aggregate<<<AGGB, 256, 0, stream>>>(bufA, csr_src, row_ptr, deg, deg_inv, agg);
    k_gemm_mfma<true><<<GB, 256, 0, stream>>>(agg, bufA, w2l, w2r, b2, bufB);
    k_aggregate<<<AGGB, 256, 0, stream>>>(bufB, csr_src, row_ptr, deg, deg_inv, agg);
    k_gemm_mfma<false><<<GB, 256, 0, stream>>>(agg, bufB, w3l, w3r, b3, bufA);

    k_head<<<HB2, 256, 0, stream>>>(bufA, batch, labels, Wlin, blin, accum);
    k_finalize<<<1, 64, 0, stream>>>(accum, (float*)d_out);
}

// Round 5
// 267.226 us; speedup vs baseline: 2.6956x; 1.1593x over previous
//
#include <hip/hip_runtime.h>
#include <hip/hip_bf16.h>

#define N_NODES 50000
#define MPAD    50048
#define N_EDGES 800000
#define DIM     128
#define N_BATCH 25000
#define NBUCK   196        // ceil(50000/256) buckets of 256 dst nodes
#define BCAP    8192       // per-bucket capacity (mean 4096, sigma 64)

typedef unsigned short u16;
typedef unsigned int   u32;
typedef unsigned long long u64;

typedef __attribute__((ext_vector_type(8))) short bf16x8;
typedef __attribute__((ext_vector_type(4))) float f32x4;

static __device__ __forceinline__ float bf2f(u16 u) {
    union { u32 i; float f; } v; v.i = ((u32)u) << 16; return v.f;
}
static __device__ __forceinline__ u16 f2bf(float f) {
    union { float f; u32 i; } v; v.f = f;
    u32 x = v.i;
    u32 r = x + 0x7fffu + ((x >> 16) & 1u);   // RTNE
    return (u16)(r >> 16);
}

// ---------------- init: bucket cursors + loss accumulator ----------------

__global__ void k_init(int* bcur, float* accum) {
    int t = threadIdx.x;
    if (t < NBUCK) bcur[t] = t * BCAP;
    if (t == 0) accum[0] = 0.f;
}

// ---- phase 1: partition edges into 196 dst-buckets (fixed capacity) ----

__global__ __launch_bounds__(256) void k_part(const int* __restrict__ src,
                                              const int* __restrict__ dst,
                                              int* __restrict__ bcur,
                                              u64* __restrict__ ebuf) {
    __shared__ int hist[NBUCK];
    __shared__ int lbase[NBUCK];
    __shared__ int gdelta[NBUCK];
    __shared__ u64 stage[4096];
    __shared__ int gaddr[4096];
    int t = threadIdx.x;
    for (int i = t; i < NBUCK; i += 256) hist[i] = 0;
    __syncthreads();

    int base = blockIdx.x * 4096;
    int cnt = N_EDGES - base; if (cnt > 4096) cnt = 4096; if (cnt < 0) cnt = 0;

    int es[16], ed[16], rr[16];
#pragma unroll
    for (int k = 0; k < 16; ++k) {
        int i = t + (k << 8);
        bool ok = i < cnt;
        int e = ok ? (base + i) : 0;
        int s = src[e], d = dst[e];
        es[k] = s; ed[k] = d;
        int r = -1;
        if (ok) r = atomicAdd(&hist[d >> 8], 1);
        rr[k] = r;
    }
    __syncthreads();

    // exclusive scan of hist[196] by wave 0 (packs this block's edges densely)
    if (t < 64) {
        int run = 0;
        for (int c = 0; c < 4; ++c) {
            int idx = c * 64 + t;
            int v = (idx < NBUCK) ? hist[idx] : 0;
            int orig = v;
            for (int off = 1; off < 64; off <<= 1) {
                int u = __shfl_up(v, off);
                if (t >= off) v += u;
            }
            int tot = __shfl(v, 63);
            if (idx < NBUCK) lbase[idx] = run + v - orig;
            run += tot;
        }
    }
    __syncthreads();

    if (t < NBUCK) {
        int c = hist[t];
        int g = atomicAdd(&bcur[t], c);      // reserve run in bucket t
        gdelta[t] = g - lbase[t];
    }
    __syncthreads();

#pragma unroll
    for (int k = 0; k < 16; ++k) {
        if (rr[k] >= 0) {
            int b = ed[k] >> 8;
            int slot = lbase[b] + rr[k];
            stage[slot] = (((u64)(u32)ed[k]) << 32) | (u32)es[k];
            gaddr[slot] = gdelta[b] + slot;
        }
    }
    __syncthreads();

    for (int i = t; i < cnt; i += 256) {
        ebuf[gaddr[i]] = stage[i];
    }
}

// ---- scan bucket counts -> global bucket bases (1 wave) ----

__global__ void k_bscan(const int* __restrict__ bcur, int* __restrict__ bbase) {
    int t = threadIdx.x;   // 64 threads
    int run = 0;
    for (int c = 0; c < 4; ++c) {
        int idx = c * 64 + t;
        int v = (idx < NBUCK) ? (bcur[idx] - idx * BCAP) : 0;
        int orig = v;
        for (int off = 1; off < 64; off <<= 1) {
            int u = __shfl_up(v, off);
            if (t >= off) v += u;
        }
        int tot = __shfl(v, 63);
        if (idx < NBUCK) bbase[idx] = run + v - orig;
        run += tot;
    }
}

// ---- phase 2: per-bucket: node degrees + row_ptr + coalesced csr scatter ----

__global__ __launch_bounds__(256) void k_build(const u64* __restrict__ ebuf,
                                               const int* __restrict__ bcur,
                                               const int* __restrict__ bbase,
                                               int* __restrict__ row_ptr,
                                               int* __restrict__ deg,
                                               float* __restrict__ deg_inv,
                                               int* __restrict__ csr_src) {
    __shared__ int cnt256[256];
    __shared__ int sh[256];
    __shared__ int cur[256];
    int b  = blockIdx.x;
    int t  = threadIdx.x;
    int n0 = b << 8;
    cnt256[t] = 0;
    __syncthreads();

    int cnt = bcur[b] - b * BCAP;
    const u64* eb = ebuf + (size_t)b * BCAP;
    for (int i = t; i < cnt; i += 256) {
        int d = (int)(eb[i] >> 32);
        atomicAdd(&cnt256[d - n0], 1);
    }
    __syncthreads();

    int myc = cnt256[t];
    sh[t] = myc;
    __syncthreads();
    for (int off = 1; off < 256; off <<= 1) {
        int x = (t >= off) ? sh[t - off] : 0;
        __syncthreads();
        sh[t] += x;
        __syncthreads();
    }
    int rp = bbase[b] + sh[t] - myc;
    int n  = n0 + t;
    if (n < N_NODES) {
        row_ptr[n] = rp;
        deg[n]     = myc;
        deg_inv[n] = 1.0f / (float)(myc < 1 ? 1 : myc);
    }
    cur[t] = rp;
    __syncthreads();

    for (int i = t; i < cnt; i += 256) {
        u64 p = eb[i];
        int d = (int)(p >> 32);
        int s = (int)(u32)p;
        int pos = atomicAdd(&cur[d - n0], 1);
        csr_src[pos] = s;
    }
}

// ---------------- casts ----------------

__global__ void k_cast_x(const float* __restrict__ x, u16* __restrict__ xb) {
    int gid = blockIdx.x * 256 + threadIdx.x;
    int row = gid >> 4;
    int c8  = (gid & 15) << 3;
    u32 outw[4];
    if (row < N_NODES) {
        const float4* p = (const float4*)(x + (size_t)row * DIM + c8);
        float4 v0 = p[0], v1 = p[1];
        outw[0] = (u32)f2bf(v0.x) | ((u32)f2bf(v0.y) << 16);
        outw[1] = (u32)f2bf(v0.z) | ((u32)f2bf(v0.w) << 16);
        outw[2] = (u32)f2bf(v1.x) | ((u32)f2bf(v1.y) << 16);
        outw[3] = (u32)f2bf(v1.z) | ((u32)f2bf(v1.w) << 16);
    } else {
        outw[0] = outw[1] = outw[2] = outw[3] = 0;
    }
    *(uint4*)(xb + (size_t)row * DIM + c8) = *(uint4*)outw;
}

__global__ void k_cast_w(const float* __restrict__ W1l, const float* __restrict__ W1r,
                         const float* __restrict__ W2l, const float* __restrict__ W2r,
                         const float* __restrict__ W3l, const float* __restrict__ W3r,
                         u16* __restrict__ out) {
    int i = blockIdx.x * 256 + threadIdx.x;
    int mat = i >> 14, off = i & 16383;
    const float* src = (mat == 0) ? W1l : (mat == 1) ? W1r : (mat == 2) ? W2l
                     : (mat == 3) ? W2r : (mat == 4) ? W3l : W3r;
    out[i] = f2bf(src[off]);
}

// ------- mean aggregation: 16 lanes/node, 4 nodes/wave, 8-deep uint4 gathers -------

__global__ __launch_bounds__(256) void k_aggregate(
    const u16* __restrict__ h, const int* __restrict__ csr_src,
    const int* __restrict__ row_ptr, const int* __restrict__ deg,
    const float* __restrict__ deg_inv, u16* __restrict__ agg) {
    int t    = threadIdx.x;
    int lane = t & 63;
    int sub  = lane & 15;
    int node = blockIdx.x * 16 + ((t >> 6) << 2) + (lane >> 4);
    size_t obase = (size_t)node * DIM + sub * 8;
    if (node >= N_NODES) {
        if (node < MPAD) { uint4 z = {0, 0, 0, 0}; *(uint4*)(agg + obase) = z; }
        return;
    }
    int start = row_ptr[node];
    int cnt   = deg[node];
    int gb    = lane & 48;
    float a0 = 0, a1 = 0, a2 = 0, a3 = 0, a4 = 0, a5 = 0, a6 = 0, a7 = 0;

#define ACC(u) { a0 += bf2f((u16)((u).x & 0xffffu)); a1 += bf2f((u16)((u).x >> 16)); \
                 a2 += bf2f((u16)((u).y & 0xffffu)); a3 += bf2f((u16)((u).y >> 16)); \
                 a4 += bf2f((u16)((u).z & 0xffffu)); a5 += bf2f((u16)((u).z >> 16)); \
                 a6 += bf2f((u16)((u).w & 0xffffu)); a7 += bf2f((u16)((u).w >> 16)); }

    for (int c0 = 0; c0 < cnt; c0 += 16) {
        int rem = cnt - c0; if (rem > 16) rem = 16;
        int sidx = 0;
        if (sub < rem) sidx = csr_src[start + c0 + sub];
        int j = 0;
        for (; j + 8 <= rem; j += 8) {
            int i0 = __shfl(sidx, gb + j);
            int i1 = __shfl(sidx, gb + j + 1);
            int i2 = __shfl(sidx, gb + j + 2);
            int i3 = __shfl(sidx, gb + j + 3);
            int i4 = __shfl(sidx, gb + j + 4);
            int i5 = __shfl(sidx, gb + j + 5);
            int i6 = __shfl(sidx, gb + j + 6);
            int i7 = __shfl(sidx, gb + j + 7);
            uint4 r0 = *(const uint4*)(h + (size_t)i0 * DIM + sub * 8);
            uint4 r1 = *(const uint4*)(h + (size_t)i1 * DIM + sub * 8);
            uint4 r2 = *(const uint4*)(h + (size_t)i2 * DIM + sub * 8);
            uint4 r3 = *(const uint4*)(h + (size_t)i3 * DIM + sub * 8);
            uint4 r4 = *(const uint4*)(h + (size_t)i4 * DIM + sub * 8);
            uint4 r5 = *(const uint4*)(h + (size_t)i5 * DIM + sub * 8);
            uint4 r6 = *(const uint4*)(h + (size_t)i6 * DIM + sub * 8);
            uint4 r7 = *(const uint4*)(h + (size_t)i7 * DIM + sub * 8);
            ACC(r0); ACC(r1); ACC(r2); ACC(r3);
            ACC(r4); ACC(r5); ACC(r6); ACC(r7);
        }
        for (; j + 4 <= rem; j += 4) {
            int i0 = __shfl(sidx, gb + j);
            int i1 = __shfl(sidx, gb + j + 1);
            int i2 = __shfl(sidx, gb + j + 2);
            int i3 = __shfl(sidx, gb + j + 3);
            uint4 r0 = *(const uint4*)(h + (size_t)i0 * DIM + sub * 8);
            uint4 r1 = *(const uint4*)(h + (size_t)i1 * DIM + sub * 8);
            uint4 r2 = *(const uint4*)(h + (size_t)i2 * DIM + sub * 8);
            uint4 r3 = *(const uint4*)(h + (size_t)i3 * DIM + sub * 8);
            ACC(r0); ACC(r1); ACC(r2); ACC(r3);
        }
        for (; j < rem; ++j) {
            int i0 = __shfl(sidx, gb + j);
            uint4 r0 = *(const uint4*)(h + (size_t)i0 * DIM + sub * 8);
            ACC(r0);
        }
    }
#undef ACC
    float inv = deg_inv[node];
    a0 *= inv; a1 *= inv; a2 *= inv; a3 *= inv;
    a4 *= inv; a5 *= inv; a6 *= inv; a7 *= inv;
    uint4 o;
    o.x = (u32)f2bf(a0) | ((u32)f2bf(a1) << 16);
    o.y = (u32)f2bf(a2) | ((u32)f2bf(a3) << 16);
    o.z = (u32)f2bf(a4) | ((u32)f2bf(a5) << 16);
    o.w = (u32)f2bf(a6) | ((u32)f2bf(a7) << 16);
    *(uint4*)(agg + obase) = o;
}

// ---------------- MFMA GEMM: out = act(agg@Wl^T + b + h@Wr^T) ----------------

template <bool RELU>
__global__ __launch_bounds__(256) void k_gemm_mfma(
    const u16* __restrict__ agg, const u16* __restrict__ h,
    const u16* __restrict__ Wl, const u16* __restrict__ Wr,
    const float* __restrict__ bias, u16* __restrict__ out) {
    const int lane = threadIdx.x & 63;
    const int wid  = threadIdx.x >> 6;
    const int m0   = (blockIdx.x * 4 + wid) * 16;
    const int fr   = lane & 15;
    const int kq   = (lane >> 4) << 3;

    bf16x8 aF[2][4];
    const u16* pa = agg + (size_t)(m0 + fr) * DIM + kq;
    const u16* ph = h   + (size_t)(m0 + fr) * DIM + kq;
#pragma unroll
    for (int kt = 0; kt < 4; ++kt) {
        aF[0][kt] = *(const bf16x8*)(pa + kt * 32);
        aF[1][kt] = *(const bf16x8*)(ph + kt * 32);
    }

    const int rbase = m0 + ((lane >> 4) << 2);
#pragma unroll
    for (int nt = 0; nt < 8; ++nt) {
        const u16* pwl = Wl + (size_t)(nt * 16 + fr) * DIM + kq;
        const u16* pwr = Wr + (size_t)(nt * 16 + fr) * DIM + kq;
        f32x4 acc = {0.f, 0.f, 0.f, 0.f};
#pragma unroll
        for (int kt = 0; kt < 4; ++kt) {
            bf16x8 w = *(const bf16x8*)(pwl + kt * 32);
            acc = __builtin_amdgcn_mfma_f32_16x16x32_bf16(aF[0][kt], w, acc, 0, 0, 0);
        }
#pragma unroll
        for (int kt = 0; kt < 4; ++kt) {
            bf16x8 w = *(const bf16x8*)(pwr + kt * 32);
            acc = __builtin_amdgcn_mfma_f32_16x16x32_bf16(aF[1][kt], w, acc, 0, 0, 0);
        }
        int col = nt * 16 + fr;
        float b = bias[col];
#pragma unroll
        for (int j = 0; j < 4; ++j) {
            float v = acc[j] + b;
            if (RELU) v = fmaxf(v, 0.f);
            out[(size_t)(rbase + j) * DIM + col] = f2bf(v);
        }
    }
}

// ---------------- head: 16 lanes per sample, 4 samples/wave ----------------

__global__ __launch_bounds__(256) void k_head(
    const u16* __restrict__ h3, const int* __restrict__ batch,
    const int* __restrict__ labels, const float* __restrict__ Wlin,
    const float* __restrict__ blin, float* __restrict__ accum) {
    __shared__ float wsh[256];
    __shared__ float red[4];
    int t = threadIdx.x;
    wsh[t] = Wlin[t];
    __syncthreads();

    int lane = t & 63;
    int g    = lane >> 4;
    int sub  = lane & 15;
    int wv   = (blockIdx.x * 256 + t) >> 6;
    int samp = wv * 4 + g;

    float contrib = 0.f;
    float z0 = 0.f, z1 = 0.f;
    int n = 0;
    if (samp < N_BATCH) {
        n = batch[samp];
        uint4 u = *(const uint4*)(h3 + (size_t)n * DIM + sub * 8);
        const u32* uw = (const u32*)&u;
        int cb = sub * 8;
#pragma unroll
        for (int q = 0; q < 4; ++q) {
            float hlo = bf2f((u16)(uw[q] & 0xffffu));
            float hhi = bf2f((u16)(uw[q] >> 16));
            z0 += hlo * wsh[cb + q * 2]       + hhi * wsh[cb + q * 2 + 1];
            z1 += hlo * wsh[128 + cb + q * 2] + hhi * wsh[128 + cb + q * 2 + 1];
        }
    }
#pragma unroll
    for (int off = 8; off > 0; off >>= 1) {
        z0 += __shfl_xor(z0, off);
        z1 += __shfl_xor(z1, off);
    }
    if (samp < N_BATCH) {
        z0 += blin[0]; z1 += blin[1];
        float m  = fmaxf(z0, z1);
        float e0 = expf(z0 - m), e1 = expf(z1 - m);
        float s  = e0 + e1;
        float p0 = e0 / s, p1 = e1 / s;
        float m2  = fmaxf(p0, p1);
        float lse = m2 + logf(expf(p0 - m2) + expf(p1 - m2));
        int lab = labels[n];
        float lp = ((lab == 0) ? p0 : p1) - lse;
        if (sub == 0) contrib = -lp * (1.0f / (float)N_BATCH);
    }
#pragma unroll
    for (int off = 16; off < 64; off <<= 1) contrib += __shfl_xor(contrib, off);
    if (lane == 0) red[t >> 6] = contrib;
    __syncthreads();
    if (t == 0) atomicAdd(accum, red[0] + red[1] + red[2] + red[3]);
}

__global__ void k_finalize(const float* accum, float* out) {
    if (threadIdx.x == 0) out[0] = accum[0];
}

// ---------------- launch ----------------

extern "C" void kernel_launch(void* const* d_in, const int* in_sizes, int n_in,
                              void* d_out, int out_size, void* d_ws, size_t ws_size,
                              hipStream_t stream) {
    const float* x    = (const float*)d_in[0];
    const int*   eidx = (const int*)d_in[1];
    const int*   batch  = (const int*)d_in[2];
    const int*   labels = (const int*)d_in[3];
    const float* W1l = (const float*)d_in[4];
    const float* b1  = (const float*)d_in[5];
    const float* W1r = (const float*)d_in[6];
    const float* W2l = (const float*)d_in[7];
    const float* b2  = (const float*)d_in[8];
    const float* W2r = (const float*)d_in[9];
    const float* W3l = (const float*)d_in[10];
    const float* b3  = (const float*)d_in[11];
    const float* W3r = (const float*)d_in[12];
    const float* Wlin = (const float*)d_in[13];
    const float* blin = (const float*)d_in[14];

    const int* src = eidx;
    const int* dst = eidx + N_EDGES;

    size_t off = 0;
    auto alloc = [&](size_t bytes) -> char* {
        off = (off + 511) & ~(size_t)511;
        char* p = (char*)d_ws + off;
        off += bytes;
        return p;
    };
    int*   bcur    = (int*)  alloc(NBUCK * 4);
    int*   bbase   = (int*)  alloc(NBUCK * 4);
    int*   row_ptr = (int*)  alloc(N_NODES * 4);
    int*   deg     = (int*)  alloc(N_NODES * 4);
    float* deg_inv = (float*)alloc(N_NODES * 4);
    int*   csr_src = (int*)  alloc(N_EDGES * 4);
    u64*   ebuf    = (u64*)  alloc((size_t)NBUCK * BCAP * 8);
    u16*   wb      = (u16*)  alloc(6 * DIM * DIM * 2);
    u16*   xb      = (u16*)  alloc((size_t)MPAD * DIM * 2);   // reused as bufB
    u16*   agg     = (u16*)  alloc((size_t)MPAD * DIM * 2);
    u16*   bufA    = (u16*)  alloc((size_t)MPAD * DIM * 2);
    float* accum   = (float*)alloc(4);

    u16* bufB = xb;

    u16* w1l = wb + 0 * DIM * DIM;
    u16* w1r = wb + 1 * DIM * DIM;
    u16* w2l = wb + 2 * DIM * DIM;
    u16* w2r = wb + 3 * DIM * DIM;
    u16* w3l = wb + 4 * DIM * DIM;
    u16* w3r = wb + 5 * DIM * DIM;

    const int PB   = (N_EDGES + 4095) / 4096;     // 196
    const int CXB  = MPAD * 16 / 256;             // 3128
    const int CWB  = 6 * DIM * DIM / 256;         // 384
    const int AGGB = MPAD / 16;                   // 3128
    const int GB   = MPAD / 64;                   // 782
    const int HB2  = (N_BATCH + 15) / 16;         // 1563

    k_init<<<1, 256, 0, stream>>>(bcur, accum);
    k_part<<<PB, 256, 0, stream>>>(src, dst, bcur, ebuf);
    k_bscan<<<1, 64, 0, stream>>>(bcur, bbase);
    k_build<<<NBUCK, 256, 0, stream>>>(ebuf, bcur, bbase, row_ptr, deg, deg_inv, csr_src);

    k_cast_x<<<CXB, 256, 0, stream>>>(x, xb);
    k_cast_w<<<CWB, 256, 0, stream>>>(W1l, W1r, W2l, W2r, W3l, W3r, wb);

    k_aggregate<<<AGGB, 256, 0, stream>>>(xb, csr_src, row_ptr, deg, deg_inv, agg);
    k_gemm_mfma<true><<<GB, 256, 0, stream>>>(agg, xb, w1l, w1r, b1, bufA);
    k_aggregate<<<AGGB, 256, 0, stream>>>(bufA, csr_src, row_ptr, deg, deg_inv, agg);
    k_gemm_mfma<true><<<GB, 256, 0, stream>>>(agg, bufA, w2l, w2r, b2, bufB);
    k_aggregate<<<AGGB, 256, 0, stream>>>(bufB, csr_src, row_ptr, deg, deg_inv, agg);
    k_gemm_mfma<false><<<GB, 256, 0, stream>>>(agg, bufB, w3l, w3r, b3, bufA);

    k_head<<<HB2, 256, 0, stream>>>(bufA, batch, labels, Wlin, blin, accum);
    k_finalize<<<1, 64, 0, stream>>>(accum, (float*)d_out);
}

// Round 6
// 252.700 us; speedup vs baseline: 2.8506x; 1.0575x over previous
//
#include <hip/hip_runtime.h>
#include <hip/hip_bf16.h>

#define N_NODES 50000
#define MPAD    50048
#define N_EDGES 800000
#define DIM     128
#define N_BATCH 25000
#define NBUCK   196        // ceil(50000/256) buckets of 256 dst nodes
#define BCAP    8192       // per-bucket capacity (mean 4096, sigma 64)

typedef unsigned short u16;
typedef unsigned int   u32;
typedef unsigned long long u64;

typedef __attribute__((ext_vector_type(8))) short bf16x8;
typedef __attribute__((ext_vector_type(4))) float f32x4;

static __device__ __forceinline__ float bf2f(u16 u) {
    union { u32 i; float f; } v; v.i = ((u32)u) << 16; return v.f;
}
static __device__ __forceinline__ u16 f2bf(float f) {
    union { float f; u32 i; } v; v.f = f;
    u32 x = v.i;
    u32 r = x + 0x7fffu + ((x >> 16) & 1u);   // RTNE
    return (u16)(r >> 16);
}

// ---------------- init ----------------

__global__ void k_init(int* bcur, float* accum, int* hcount) {
    int t = threadIdx.x;
    if (t < NBUCK) bcur[t] = t * BCAP;
    if (t == 0) { accum[0] = 0.f; hcount[0] = 0; }
}

// ---- phase 1: partition edges into 196 dst-buckets (fixed capacity) ----

__global__ __launch_bounds__(256) void k_part(const int* __restrict__ src,
                                              const int* __restrict__ dst,
                                              int* __restrict__ bcur,
                                              u64* __restrict__ ebuf) {
    __shared__ int hist[NBUCK];
    __shared__ int lbase[NBUCK];
    __shared__ int gdelta[NBUCK];
    __shared__ u64 stage[4096];
    __shared__ int gaddr[4096];
    int t = threadIdx.x;
    for (int i = t; i < NBUCK; i += 256) hist[i] = 0;
    __syncthreads();

    int base = blockIdx.x * 4096;
    int cnt = N_EDGES - base; if (cnt > 4096) cnt = 4096; if (cnt < 0) cnt = 0;

    int es[16], ed[16], rr[16];
#pragma unroll
    for (int k = 0; k < 16; ++k) {
        int i = t + (k << 8);
        bool ok = i < cnt;
        int e = ok ? (base + i) : 0;
        int s = src[e], d = dst[e];
        es[k] = s; ed[k] = d;
        int r = -1;
        if (ok) r = atomicAdd(&hist[d >> 8], 1);
        rr[k] = r;
    }
    __syncthreads();

    if (t < 64) {
        int run = 0;
        for (int c = 0; c < 4; ++c) {
            int idx = c * 64 + t;
            int v = (idx < NBUCK) ? hist[idx] : 0;
            int orig = v;
            for (int off = 1; off < 64; off <<= 1) {
                int u = __shfl_up(v, off);
                if (t >= off) v += u;
            }
            int tot = __shfl(v, 63);
            if (idx < NBUCK) lbase[idx] = run + v - orig;
            run += tot;
        }
    }
    __syncthreads();

    if (t < NBUCK) {
        int c = hist[t];
        int g = atomicAdd(&bcur[t], c);
        gdelta[t] = g - lbase[t];
    }
    __syncthreads();

#pragma unroll
    for (int k = 0; k < 16; ++k) {
        if (rr[k] >= 0) {
            int b = ed[k] >> 8;
            int slot = lbase[b] + rr[k];
            stage[slot] = (((u64)(u32)ed[k]) << 32) | (u32)es[k];
            gaddr[slot] = gdelta[b] + slot;
        }
    }
    __syncthreads();

    for (int i = t; i < cnt; i += 256) {
        ebuf[gaddr[i]] = stage[i];
    }
}

// ---- scan bucket counts -> global bucket bases (1 wave) ----

__global__ void k_bscan(const int* __restrict__ bcur, int* __restrict__ bbase) {
    int t = threadIdx.x;
    int run = 0;
    for (int c = 0; c < 4; ++c) {
        int idx = c * 64 + t;
        int v = (idx < NBUCK) ? (bcur[idx] - idx * BCAP) : 0;
        int orig = v;
        for (int off = 1; off < 64; off <<= 1) {
            int u = __shfl_up(v, off);
            if (t >= off) v += u;
        }
        int tot = __shfl(v, 63);
        if (idx < NBUCK) bbase[idx] = run + v - orig;
        run += tot;
    }
}

// ---- phase 2: per-bucket: degrees + row_ptr + coalesced csr scatter ----

__global__ __launch_bounds__(256) void k_build(const u64* __restrict__ ebuf,
                                               const int* __restrict__ bcur,
                                               const int* __restrict__ bbase,
                                               int* __restrict__ row_ptr,
                                               int* __restrict__ deg,
                                               float* __restrict__ deg_inv,
                                               int* __restrict__ csr_src) {
    __shared__ int cnt256[256];
    __shared__ int sh[256];
    __shared__ int cur[256];
    int b  = blockIdx.x;
    int t  = threadIdx.x;
    int n0 = b << 8;
    cnt256[t] = 0;
    __syncthreads();

    int cnt = bcur[b] - b * BCAP;
    const u64* eb = ebuf + (size_t)b * BCAP;
    for (int i = t; i < cnt; i += 256) {
        int d = (int)(eb[i] >> 32);
        atomicAdd(&cnt256[d - n0], 1);
    }
    __syncthreads();

    int myc = cnt256[t];
    sh[t] = myc;
    __syncthreads();
    for (int off = 1; off < 256; off <<= 1) {
        int x = (t >= off) ? sh[t - off] : 0;
        __syncthreads();
        sh[t] += x;
        __syncthreads();
    }
    int rp = bbase[b] + sh[t] - myc;
    int n  = n0 + t;
    if (n < N_NODES) {
        row_ptr[n] = rp;
        deg[n]     = myc;
        deg_inv[n] = 1.0f / (float)(myc < 1 ? 1 : myc);
    }
    cur[t] = rp;
    __syncthreads();

    for (int i = t; i < cnt; i += 256) {
        u64 p = eb[i];
        int d = (int)(p >> 32);
        int s = (int)(u32)p;
        int pos = atomicAdd(&cur[d - n0], 1);
        csr_src[pos] = s;
    }
}

// ---------------- casts ----------------

__global__ void k_cast_x(const float* __restrict__ x, u16* __restrict__ xb) {
    int gid = blockIdx.x * 256 + threadIdx.x;
    int row = gid >> 4;
    int c8  = (gid & 15) << 3;
    u32 outw[4];
    if (row < N_NODES) {
        const float4* p = (const float4*)(x + (size_t)row * DIM + c8);
        float4 v0 = p[0], v1 = p[1];
        outw[0] = (u32)f2bf(v0.x) | ((u32)f2bf(v0.y) << 16);
        outw[1] = (u32)f2bf(v0.z) | ((u32)f2bf(v0.w) << 16);
        outw[2] = (u32)f2bf(v1.x) | ((u32)f2bf(v1.y) << 16);
        outw[3] = (u32)f2bf(v1.z) | ((u32)f2bf(v1.w) << 16);
    } else {
        outw[0] = outw[1] = outw[2] = outw[3] = 0;
    }
    *(uint4*)(xb + (size_t)row * DIM + c8) = *(uint4*)outw;
}

__global__ void k_cast_w(const float* __restrict__ W1l, const float* __restrict__ W1r,
                         const float* __restrict__ W2l, const float* __restrict__ W2r,
                         const float* __restrict__ W3l, const float* __restrict__ W3r,
                         u16* __restrict__ out) {
    int i = blockIdx.x * 256 + threadIdx.x;
    int mat = i >> 14, off = i & 16383;
    const float* src = (mat == 0) ? W1l : (mat == 1) ? W1r : (mat == 2) ? W2l
                     : (mat == 3) ? W2r : (mat == 4) ? W3l : W3r;
    out[i] = f2bf(src[off]);
}

// ---- fused SAGE layer: mean-aggregate (16 lanes/node) -> LDS tile -> MFMA ----
// Block: 256 threads = 16 nodes. LDS tile[16][128] bf16, chunk-swizzled:
// addr(row, chunk) = row*128 + ((chunk ^ (row&7)) * 8) u16s, chunk = 16B unit.
// MFMA phase: wave wid computes nt = wid*2, wid*2+1 (col tiles of 16).

template <bool RELU>
__global__ __launch_bounds__(256) void k_sage(
    const u16* __restrict__ h, const int* __restrict__ csr_src,
    const int* __restrict__ row_ptr, const int* __restrict__ deg,
    const float* __restrict__ deg_inv,
    const u16* __restrict__ Wl, const u16* __restrict__ Wr,
    const float* __restrict__ bias, u16* __restrict__ out) {
    __shared__ u16 tile[16 * 128];
    int t    = threadIdx.x;
    int lane = t & 63;
    int wid  = t >> 6;
    int sub  = lane & 15;
    int grp  = lane >> 4;
    int nloc = (wid << 2) + grp;
    int node = blockIdx.x * 16 + nloc;
    int gb   = lane & 48;

    float a0 = 0, a1 = 0, a2 = 0, a3 = 0, a4 = 0, a5 = 0, a6 = 0, a7 = 0;

#define ACC(u) { a0 += bf2f((u16)((u).x & 0xffffu)); a1 += bf2f((u16)((u).x >> 16)); \
                 a2 += bf2f((u16)((u).y & 0xffffu)); a3 += bf2f((u16)((u).y >> 16)); \
                 a4 += bf2f((u16)((u).z & 0xffffu)); a5 += bf2f((u16)((u).z >> 16)); \
                 a6 += bf2f((u16)((u).w & 0xffffu)); a7 += bf2f((u16)((u).w >> 16)); }

    if (node < N_NODES) {
        int start = row_ptr[node];
        int cnt   = deg[node];
        for (int c0 = 0; c0 < cnt; c0 += 16) {
            int rem = cnt - c0; if (rem > 16) rem = 16;
            int sidx = 0;
            if (sub < rem) sidx = csr_src[start + c0 + sub];
            int j = 0;
            for (; j + 8 <= rem; j += 8) {
                int i0 = __shfl(sidx, gb + j);
                int i1 = __shfl(sidx, gb + j + 1);
                int i2 = __shfl(sidx, gb + j + 2);
                int i3 = __shfl(sidx, gb + j + 3);
                int i4 = __shfl(sidx, gb + j + 4);
                int i5 = __shfl(sidx, gb + j + 5);
                int i6 = __shfl(sidx, gb + j + 6);
                int i7 = __shfl(sidx, gb + j + 7);
                uint4 r0 = *(const uint4*)(h + (size_t)i0 * DIM + sub * 8);
                uint4 r1 = *(const uint4*)(h + (size_t)i1 * DIM + sub * 8);
                uint4 r2 = *(const uint4*)(h + (size_t)i2 * DIM + sub * 8);
                uint4 r3 = *(const uint4*)(h + (size_t)i3 * DIM + sub * 8);
                uint4 r4 = *(const uint4*)(h + (size_t)i4 * DIM + sub * 8);
                uint4 r5 = *(const uint4*)(h + (size_t)i5 * DIM + sub * 8);
                uint4 r6 = *(const uint4*)(h + (size_t)i6 * DIM + sub * 8);
                uint4 r7 = *(const uint4*)(h + (size_t)i7 * DIM + sub * 8);
                ACC(r0); ACC(r1); ACC(r2); ACC(r3);
                ACC(r4); ACC(r5); ACC(r6); ACC(r7);
            }
            for (; j + 4 <= rem; j += 4) {
                int i0 = __shfl(sidx, gb + j);
                int i1 = __shfl(sidx, gb + j + 1);
                int i2 = __shfl(sidx, gb + j + 2);
                int i3 = __shfl(sidx, gb + j + 3);
                uint4 r0 = *(const uint4*)(h + (size_t)i0 * DIM + sub * 8);
                uint4 r1 = *(const uint4*)(h + (size_t)i1 * DIM + sub * 8);
                uint4 r2 = *(const uint4*)(h + (size_t)i2 * DIM + sub * 8);
                uint4 r3 = *(const uint4*)(h + (size_t)i3 * DIM + sub * 8);
                ACC(r0); ACC(r1); ACC(r2); ACC(r3);
            }
            for (; j < rem; ++j) {
                int i0 = __shfl(sidx, gb + j);
                uint4 r0 = *(const uint4*)(h + (size_t)i0 * DIM + sub * 8);
                ACC(r0);
            }
        }
        float inv = deg_inv[node];
        a0 *= inv; a1 *= inv; a2 *= inv; a3 *= inv;
        a4 *= inv; a5 *= inv; a6 *= inv; a7 *= inv;
    }
#undef ACC

    // pack mean row into swizzled LDS tile
    {
        uint4 o;
        o.x = (u32)f2bf(a0) | ((u32)f2bf(a1) << 16);
        o.y = (u32)f2bf(a2) | ((u32)f2bf(a3) << 16);
        o.z = (u32)f2bf(a4) | ((u32)f2bf(a5) << 16);
        o.w = (u32)f2bf(a6) | ((u32)f2bf(a7) << 16);
        int chunk = sub ^ (nloc & 7);
        *(uint4*)&tile[nloc * 128 + chunk * 8] = o;
    }
    __syncthreads();

    // MFMA phase
    const int fr = sub;
    const int kq = grp << 3;
    const int m0 = blockIdx.x * 16;
    bf16x8 aF0[4], aF1[4];
    const u16* ph = h + (size_t)(m0 + fr) * DIM + kq;
#pragma unroll
    for (int kt = 0; kt < 4; ++kt) {
        int c = (grp + kt * 4) ^ (fr & 7);
        aF0[kt] = *(const bf16x8*)&tile[fr * 128 + c * 8];
        aF1[kt] = *(const bf16x8*)(ph + kt * 32);
    }
    const int rbase = m0 + (grp << 2);
#pragma unroll
    for (int q = 0; q < 2; ++q) {
        int nt = wid * 2 + q;
        const u16* pwl = Wl + (size_t)(nt * 16 + fr) * DIM + kq;
        const u16* pwr = Wr + (size_t)(nt * 16 + fr) * DIM + kq;
        f32x4 acc = {0.f, 0.f, 0.f, 0.f};
#pragma unroll
        for (int kt = 0; kt < 4; ++kt) {
            bf16x8 w = *(const bf16x8*)(pwl + kt * 32);
            acc = __builtin_amdgcn_mfma_f32_16x16x32_bf16(aF0[kt], w, acc, 0, 0, 0);
        }
#pragma unroll
        for (int kt = 0; kt < 4; ++kt) {
            bf16x8 w = *(const bf16x8*)(pwr + kt * 32);
            acc = __builtin_amdgcn_mfma_f32_16x16x32_bf16(aF1[kt], w, acc, 0, 0, 0);
        }
        int col = nt * 16 + fr;
        float b = bias[col];
#pragma unroll
        for (int j = 0; j < 4; ++j) {
            float v = acc[j] + b;
            if (RELU) v = fmaxf(v, 0.f);
            out[(size_t)(rbase + j) * DIM + col] = f2bf(v);
        }
    }
}

// ---------------- head: softmax -> log_softmax -> NLL mean (+finalize) ----------------

__global__ __launch_bounds__(256) void k_head(
    const u16* __restrict__ h3, const int* __restrict__ batch,
    const int* __restrict__ labels, const float* __restrict__ Wlin,
    const float* __restrict__ blin, float* __restrict__ accum,
    int* __restrict__ hcount, float* __restrict__ out) {
    __shared__ float wsh[256];
    __shared__ float red[4];
    int t = threadIdx.x;
    wsh[t] = Wlin[t];
    __syncthreads();

    int lane = t & 63;
    int g    = lane >> 4;
    int sub  = lane & 15;
    int wv   = (blockIdx.x * 256 + t) >> 6;
    int samp = wv * 4 + g;

    float contrib = 0.f;
    float z0 = 0.f, z1 = 0.f;
    int n = 0;
    if (samp < N_BATCH) {
        n = batch[samp];
        uint4 u = *(const uint4*)(h3 + (size_t)n * DIM + sub * 8);
        const u32* uw = (const u32*)&u;
        int cb = sub * 8;
#pragma unroll
        for (int q = 0; q < 4; ++q) {
            float hlo = bf2f((u16)(uw[q] & 0xffffu));
            float hhi = bf2f((u16)(uw[q] >> 16));
            z0 += hlo * wsh[cb + q * 2]       + hhi * wsh[cb + q * 2 + 1];
            z1 += hlo * wsh[128 + cb + q * 2] + hhi * wsh[128 + cb + q * 2 + 1];
        }
    }
#pragma unroll
    for (int off = 8; off > 0; off >>= 1) {
        z0 += __shfl_xor(z0, off);
        z1 += __shfl_xor(z1, off);
    }
    if (samp < N_BATCH) {
        z0 += blin[0]; z1 += blin[1];
        float m  = fmaxf(z0, z1);
        float e0 = expf(z0 - m), e1 = expf(z1 - m);
        float s  = e0 + e1;
        float p0 = e0 / s, p1 = e1 / s;
        float m2  = fmaxf(p0, p1);
        float lse = m2 + logf(expf(p0 - m2) + expf(p1 - m2));
        int lab = labels[n];
        float lp = ((lab == 0) ? p0 : p1) - lse;
        if (sub == 0) contrib = -lp * (1.0f / (float)N_BATCH);
    }
#pragma unroll
    for (int off = 16; off < 64; off <<= 1) contrib += __shfl_xor(contrib, off);
    if (lane == 0) red[t >> 6] = contrib;
    __syncthreads();
    if (t == 0) {
        atomicAdd(accum, red[0] + red[1] + red[2] + red[3]);
        __threadfence();
        int c = atomicAdd(hcount, 1);
        if (c == (int)gridDim.x - 1) {
            float v = atomicAdd(accum, 0.0f);   // coherent read of final sum
            out[0] = v;
        }
    }
}

// ---------------- launch ----------------

extern "C" void kernel_launch(void* const* d_in, const int* in_sizes, int n_in,
                              void* d_out, int out_size, void* d_ws, size_t ws_size,
                              hipStream_t stream) {
    const float* x    = (const float*)d_in[0];
    const int*   eidx = (const int*)d_in[1];
    const int*   batch  = (const int*)d_in[2];
    const int*   labels = (const int*)d_in[3];
    const float* W1l = (const float*)d_in[4];
    const float* b1  = (const float*)d_in[5];
    const float* W1r = (const float*)d_in[6];
    const float* W2l = (const float*)d_in[7];
    const float* b2  = (const float*)d_in[8];
    const float* W2r = (const float*)d_in[9];
    const float* W3l = (const float*)d_in[10];
    const float* b3  = (const float*)d_in[11];
    const float* W3r = (const float*)d_in[12];
    const float* Wlin = (const float*)d_in[13];
    const float* blin = (const float*)d_in[14];

    const int* src = eidx;
    const int* dst = eidx + N_EDGES;

    size_t off = 0;
    auto alloc = [&](size_t bytes) -> char* {
        off = (off + 511) & ~(size_t)511;
        char* p = (char*)d_ws + off;
        off += bytes;
        return p;
    };
    int*   bcur    = (int*)  alloc(NBUCK * 4);
    int*   bbase   = (int*)  alloc(NBUCK * 4);
    int*   row_ptr = (int*)  alloc(N_NODES * 4);
    int*   deg     = (int*)  alloc(N_NODES * 4);
    float* deg_inv = (float*)alloc(N_NODES * 4);
    int*   csr_src = (int*)  alloc(N_EDGES * 4);
    u64*   ebuf    = (u64*)  alloc((size_t)NBUCK * BCAP * 8);
    u16*   wb      = (u16*)  alloc(6 * DIM * DIM * 2);
    u16*   xb      = (u16*)  alloc((size_t)MPAD * DIM * 2);   // reused as bufB
    u16*   agg     = (u16*)  alloc((size_t)MPAD * DIM * 2);   // (kept: scratch)
    u16*   bufA    = (u16*)  alloc((size_t)MPAD * DIM * 2);
    float* accum   = (float*)alloc(4);
    int*   hcount  = (int*)  alloc(4);
    (void)agg;

    u16* bufB = xb;

    u16* w1l = wb + 0 * DIM * DIM;
    u16* w1r = wb + 1 * DIM * DIM;
    u16* w2l = wb + 2 * DIM * DIM;
    u16* w2r = wb + 3 * DIM * DIM;
    u16* w3l = wb + 4 * DIM * DIM;
    u16* w3r = wb + 5 * DIM * DIM;

    const int PB   = (N_EDGES + 4095) / 4096;     // 196
    const int CXB  = MPAD * 16 / 256;             // 3128
    const int CWB  = 6 * DIM * DIM / 256;         // 384
    const int SGB  = MPAD / 16;                   // 3128
    const int HB2  = (N_BATCH + 15) / 16;         // 1563

    k_init<<<1, 256, 0, stream>>>(bcur, accum, hcount);
    k_part<<<PB, 256, 0, stream>>>(src, dst, bcur, ebuf);
    k_bscan<<<1, 64, 0, stream>>>(bcur, bbase);
    k_build<<<NBUCK, 256, 0, stream>>>(ebuf, bcur, bbase, row_ptr, deg, deg_inv, csr_src);

    k_cast_x<<<CXB, 256, 0, stream>>>(x, xb);
    k_cast_w<<<CWB, 256, 0, stream>>>(W1l, W1r, W2l, W2r, W3l, W3r, wb);

    k_sage<true><<<SGB, 256, 0, stream>>>(xb, csr_src, row_ptr, deg, deg_inv,
                                          w1l, w1r, b1, bufA);
    k_sage<true><<<SGB, 256, 0, stream>>>(bufA, csr_src, row_ptr, deg, deg_inv,
                                          w2l, w2r, b2, bufB);
    k_sage<false><<<SGB, 256, 0, stream>>>(bufB, csr_src, row_ptr, deg, deg_inv,
                                           w3l, w3r, b3, bufA);

    k_head<<<HB2, 256, 0, stream>>>(bufA, batch, labels, Wlin, blin,
                                    accum, hcount, (float*)d_out);
}

// Round 7
// 218.708 us; speedup vs baseline: 3.2937x; 1.1554x over previous
//
#include <hip/hip_runtime.h>
#include <hip/hip_bf16.h>

#define N_NODES 50000
#define MPAD    50048
#define N_EDGES 800000
#define DIM     128
#define N_BATCH 25000
#define NBUCK   196        // ceil(50000/256) buckets of 256 dst nodes
#define BCAP    8192       // per-bucket capacity (mean 4096, sigma 64)
#define NBIN    64         // degree bins for counting sort

typedef unsigned short u16;
typedef unsigned int   u32;
typedef unsigned char  u8;
typedef unsigned long long u64;

typedef __attribute__((ext_vector_type(8))) short bf16x8;
typedef __attribute__((ext_vector_type(4))) float f32x4;

static __device__ __forceinline__ float bf2f(u16 u) {
    union { u32 i; float f; } v; v.i = ((u32)u) << 16; return v.f;
}
static __device__ __forceinline__ u16 f2bf(float f) {
    union { float f; u32 i; } v; v.f = f;
    u32 x = v.i;
    u32 r = x + 0x7fffu + ((x >> 16) & 1u);   // RTNE
    return (u16)(r >> 16);
}

// ---------------- init: cursors, accumulators, masks, bins ----------------

__global__ void k_init(int* bcur, float* accum, int* hcount,
                       u8* mask, int* h1g, int* h3g) {
    int gid = blockIdx.x * 256 + threadIdx.x;
    if (gid < NBUCK) bcur[gid] = gid * BCAP;
    if (gid < NBIN) { h1g[gid] = 0; h3g[gid] = 0; }
    if (gid < N_NODES) mask[gid] = 0;
    if (gid == 0) { accum[0] = 0.f; hcount[0] = 0; }
}

__global__ void k_mark(const int* __restrict__ batch, u8* __restrict__ mask) {
    int s = blockIdx.x * 256 + threadIdx.x;
    if (s < N_BATCH) mask[batch[s]] = 1;
}

// ---- phase 1: partition edges into 196 dst-buckets (fixed capacity) ----

__global__ __launch_bounds__(256) void k_part(const int* __restrict__ src,
                                              const int* __restrict__ dst,
                                              int* __restrict__ bcur,
                                              u64* __restrict__ ebuf) {
    __shared__ int hist[NBUCK];
    __shared__ int lbase[NBUCK];
    __shared__ int gdelta[NBUCK];
    __shared__ u64 stage[4096];
    __shared__ int gaddr[4096];
    int t = threadIdx.x;
    for (int i = t; i < NBUCK; i += 256) hist[i] = 0;
    __syncthreads();

    int base = blockIdx.x * 4096;
    int cnt = N_EDGES - base; if (cnt > 4096) cnt = 4096; if (cnt < 0) cnt = 0;

    int es[16], ed[16], rr[16];
#pragma unroll
    for (int k = 0; k < 16; ++k) {
        int i = t + (k << 8);
        bool ok = i < cnt;
        int e = ok ? (base + i) : 0;
        int s = src[e], d = dst[e];
        es[k] = s; ed[k] = d;
        int r = -1;
        if (ok) r = atomicAdd(&hist[d >> 8], 1);
        rr[k] = r;
    }
    __syncthreads();

    if (t < 64) {
        int run = 0;
        for (int c = 0; c < 4; ++c) {
            int idx = c * 64 + t;
            int v = (idx < NBUCK) ? hist[idx] : 0;
            int orig = v;
            for (int off = 1; off < 64; off <<= 1) {
                int u = __shfl_up(v, off);
                if (t >= off) v += u;
            }
            int tot = __shfl(v, 63);
            if (idx < NBUCK) lbase[idx] = run + v - orig;
            run += tot;
        }
    }
    __syncthreads();

    if (t < NBUCK) {
        int c = hist[t];
        int g = atomicAdd(&bcur[t], c);
        gdelta[t] = g - lbase[t];
    }
    __syncthreads();

#pragma unroll
    for (int k = 0; k < 16; ++k) {
        if (rr[k] >= 0) {
            int b = ed[k] >> 8;
            int slot = lbase[b] + rr[k];
            stage[slot] = (((u64)(u32)ed[k]) << 32) | (u32)es[k];
            gaddr[slot] = gdelta[b] + slot;
        }
    }
    __syncthreads();

    for (int i = t; i < cnt; i += 256) {
        ebuf[gaddr[i]] = stage[i];
    }
}

// ---- scan bucket counts -> global bucket bases (1 wave) ----

__global__ void k_bscan(const int* __restrict__ bcur, int* __restrict__ bbase) {
    int t = threadIdx.x;
    int run = 0;
    for (int c = 0; c < 4; ++c) {
        int idx = c * 64 + t;
        int v = (idx < NBUCK) ? (bcur[idx] - idx * BCAP) : 0;
        int orig = v;
        for (int off = 1; off < 64; off <<= 1) {
            int u = __shfl_up(v, off);
            if (t >= off) v += u;
        }
        int tot = __shfl(v, 63);
        if (idx < NBUCK) bbase[idx] = run + v - orig;
        run += tot;
    }
}

// ---- phase 2: per-bucket: degrees + row_ptr + csr scatter + degree hist ----

__global__ __launch_bounds__(256) void k_build(const u64* __restrict__ ebuf,
                                               const int* __restrict__ bcur,
                                               const int* __restrict__ bbase,
                                               const u8* __restrict__ mask,
                                               int* __restrict__ row_ptr,
                                               int* __restrict__ deg,
                                               float* __restrict__ deg_inv,
                                               int* __restrict__ csr_src,
                                               int* __restrict__ h1g,
                                               int* __restrict__ h3g) {
    __shared__ int cnt256[256];
    __shared__ int sh[256];
    __shared__ int cur[256];
    __shared__ int bh1[NBIN];
    __shared__ int bh3[NBIN];
    int b  = blockIdx.x;
    int t  = threadIdx.x;
    int n0 = b << 8;
    cnt256[t] = 0;
    if (t < NBIN) { bh1[t] = 0; bh3[t] = 0; }
    __syncthreads();

    int cnt = bcur[b] - b * BCAP;
    const u64* eb = ebuf + (size_t)b * BCAP;
    for (int i = t; i < cnt; i += 256) {
        int d = (int)(eb[i] >> 32);
        atomicAdd(&cnt256[d - n0], 1);
    }
    __syncthreads();

    int myc = cnt256[t];
    sh[t] = myc;
    __syncthreads();
    for (int off = 1; off < 256; off <<= 1) {
        int x = (t >= off) ? sh[t - off] : 0;
        __syncthreads();
        sh[t] += x;
        __syncthreads();
    }
    int rp = bbase[b] + sh[t] - myc;
    int n  = n0 + t;
    if (n < N_NODES) {
        row_ptr[n] = rp;
        deg[n]     = myc;
        deg_inv[n] = 1.0f / (float)(myc < 1 ? 1 : myc);
        int bin = myc < NBIN ? myc : NBIN - 1;
        atomicAdd(&bh1[bin], 1);
        if (mask[n]) atomicAdd(&bh3[bin], 1);
    }
    cur[t] = rp;
    __syncthreads();

    for (int i = t; i < cnt; i += 256) {
        u64 p = eb[i];
        int d = (int)(p >> 32);
        int s = (int)(u32)p;
        int pos = atomicAdd(&cur[d - n0], 1);
        csr_src[pos] = s;
    }
    __syncthreads();
    if (t < NBIN) {
        if (bh1[t]) atomicAdd(&h1g[t], bh1[t]);
        if (bh3[t]) atomicAdd(&h3g[t], bh3[t]);
    }
}

// ---- degree-bin scan: h1g/h3g (counts) -> bases (in place), n3 out ----

__global__ void k_dscan(int* __restrict__ h1g, int* __restrict__ h3g,
                        int* __restrict__ n3out) {
    int t = threadIdx.x;   // 64
    int v1 = h1g[t], v3 = h3g[t];
    int o1 = v1, o3 = v3;
    for (int off = 1; off < 64; off <<= 1) {
        int u1 = __shfl_up(v1, off);
        int u3 = __shfl_up(v3, off);
        if (t >= off) { v1 += u1; v3 += u3; }
    }
    if (t == 63) n3out[0] = v3;
    h1g[t] = v1 - o1;
    h3g[t] = v3 - o3;
}

// ---- counting-sort scatter: node ids into degree-sorted worklists ----

__global__ __launch_bounds__(256) void k_dscatter(const int* __restrict__ deg,
                                                  const u8* __restrict__ mask,
                                                  int* __restrict__ h1g,
                                                  int* __restrict__ h3g,
                                                  int* __restrict__ wl1,
                                                  int* __restrict__ wl3) {
    __shared__ int bh1[NBIN], bh3[NBIN], bb1[NBIN], bb3[NBIN];
    int t = threadIdx.x;
    int n = blockIdx.x * 256 + t;
    if (t < NBIN) { bh1[t] = 0; bh3[t] = 0; }
    __syncthreads();
    bool valid = n < N_NODES;
    int d = 0, r1 = -1, r3 = -1;
    if (valid) {
        d = deg[n]; if (d >= NBIN) d = NBIN - 1;
        r1 = atomicAdd(&bh1[d], 1);
        if (mask[n]) r3 = atomicAdd(&bh3[d], 1);
    }
    __syncthreads();
    if (t < NBIN) {
        bb1[t] = atomicAdd(&h1g[t], bh1[t]);
        bb3[t] = atomicAdd(&h3g[t], bh3[t]);
    }
    __syncthreads();
    if (valid) {
        wl1[bb1[d] + r1] = n;
        if (r3 >= 0) wl3[bb3[d] + r3] = n;
    }
}

// ---------------- casts ----------------

__global__ void k_cast_x(const float* __restrict__ x, u16* __restrict__ xb) {
    int gid = blockIdx.x * 256 + threadIdx.x;
    int row = gid >> 4;
    int c8  = (gid & 15) << 3;
    u32 outw[4];
    if (row < N_NODES) {
        const float4* p = (const float4*)(x + (size_t)row * DIM + c8);
        float4 v0 = p[0], v1 = p[1];
        outw[0] = (u32)f2bf(v0.x) | ((u32)f2bf(v0.y) << 16);
        outw[1] = (u32)f2bf(v0.z) | ((u32)f2bf(v0.w) << 16);
        outw[2] = (u32)f2bf(v1.x) | ((u32)f2bf(v1.y) << 16);
        outw[3] = (u32)f2bf(v1.z) | ((u32)f2bf(v1.w) << 16);
    } else {
        outw[0] = outw[1] = outw[2] = outw[3] = 0;
    }
    *(uint4*)(xb + (size_t)row * DIM + c8) = *(uint4*)outw;
}

__global__ void k_cast_w(const float* __restrict__ W1l, const float* __restrict__ W1r,
                         const float* __restrict__ W2l, const float* __restrict__ W2r,
                         const float* __restrict__ W3l, const float* __restrict__ W3r,
                         u16* __restrict__ out) {
    int i = blockIdx.x * 256 + threadIdx.x;
    int mat = i >> 14, off = i & 16383;
    const float* src = (mat == 0) ? W1l : (mat == 1) ? W1r : (mat == 2) ? W2l
                     : (mat == 3) ? W2r : (mat == 4) ? W3l : W3r;
    out[i] = f2bf(src[off]);
}

// ---- fused SAGE layer over a worklist: aggregate -> LDS tile -> MFMA ----
// Block: 256 threads = 16 worklist slots. PRUNED: count read from wlN.

template <bool RELU, bool PRUNED>
__global__ __launch_bounds__(256) void k_sage(
    const u16* __restrict__ h, const int* __restrict__ csr_src,
    const int* __restrict__ row_ptr, const int* __restrict__ deg,
    const float* __restrict__ deg_inv,
    const int* __restrict__ wl, const int* __restrict__ wlN,
    const u16* __restrict__ Wl, const u16* __restrict__ Wr,
    const float* __restrict__ bias, u16* __restrict__ out) {
    __shared__ u16 tile[16 * 128];
    __shared__ int wlid[16];
    int nwl = PRUNED ? wlN[0] : N_NODES;
    int m0  = blockIdx.x * 16;
    if (m0 >= nwl) return;

    int t    = threadIdx.x;
    int lane = t & 63;
    int wid  = t >> 6;
    int sub  = lane & 15;
    int grp  = lane >> 4;
    int nloc = (wid << 2) + grp;
    int gb   = lane & 48;
    int node = (m0 + nloc < nwl) ? wl[m0 + nloc] : -1;
    if (sub == 0) wlid[nloc] = node;

    float a0 = 0, a1 = 0, a2 = 0, a3 = 0, a4 = 0, a5 = 0, a6 = 0, a7 = 0;

#define ACC(u) { a0 += bf2f((u16)((u).x & 0xffffu)); a1 += bf2f((u16)((u).x >> 16)); \
                 a2 += bf2f((u16)((u).y & 0xffffu)); a3 += bf2f((u16)((u).y >> 16)); \
                 a4 += bf2f((u16)((u).z & 0xffffu)); a5 += bf2f((u16)((u).z >> 16)); \
                 a6 += bf2f((u16)((u).w & 0xffffu)); a7 += bf2f((u16)((u).w >> 16)); }

    if (node >= 0) {
        int start = row_ptr[node];
        int cnt   = deg[node];
        for (int c0 = 0; c0 < cnt; c0 += 16) {
            int rem = cnt - c0; if (rem > 16) rem = 16;
            int sidx = 0;
            if (sub < rem) sidx = csr_src[start + c0 + sub];
            int j = 0;
            for (; j + 8 <= rem; j += 8) {
                int i0 = __shfl(sidx, gb + j);
                int i1 = __shfl(sidx, gb + j + 1);
                int i2 = __shfl(sidx, gb + j + 2);
                int i3 = __shfl(sidx, gb + j + 3);
                int i4 = __shfl(sidx, gb + j + 4);
                int i5 = __shfl(sidx, gb + j + 5);
                int i6 = __shfl(sidx, gb + j + 6);
                int i7 = __shfl(sidx, gb + j + 7);
                uint4 r0 = *(const uint4*)(h + (size_t)i0 * DIM + sub * 8);
                uint4 r1 = *(const uint4*)(h + (size_t)i1 * DIM + sub * 8);
                uint4 r2 = *(const uint4*)(h + (size_t)i2 * DIM + sub * 8);
                uint4 r3 = *(const uint4*)(h + (size_t)i3 * DIM + sub * 8);
                uint4 r4 = *(const uint4*)(h + (size_t)i4 * DIM + sub * 8);
                uint4 r5 = *(const uint4*)(h + (size_t)i5 * DIM + sub * 8);
                uint4 r6 = *(const uint4*)(h + (size_t)i6 * DIM + sub * 8);
                uint4 r7 = *(const uint4*)(h + (size_t)i7 * DIM + sub * 8);
                ACC(r0); ACC(r1); ACC(r2); ACC(r3);
                ACC(r4); ACC(r5); ACC(r6); ACC(r7);
            }
            for (; j + 4 <= rem; j += 4) {
                int i0 = __shfl(sidx, gb + j);
                int i1 = __shfl(sidx, gb + j + 1);
                int i2 = __shfl(sidx, gb + j + 2);
                int i3 = __shfl(sidx, gb + j + 3);
                uint4 r0 = *(const uint4*)(h + (size_t)i0 * DIM + sub * 8);
                uint4 r1 = *(const uint4*)(h + (size_t)i1 * DIM + sub * 8);
                uint4 r2 = *(const uint4*)(h + (size_t)i2 * DIM + sub * 8);
                uint4 r3 = *(const uint4*)(h + (size_t)i3 * DIM + sub * 8);
                ACC(r0); ACC(r1); ACC(r2); ACC(r3);
            }
            for (; j < rem; ++j) {
                int i0 = __shfl(sidx, gb + j);
                uint4 r0 = *(const uint4*)(h + (size_t)i0 * DIM + sub * 8);
                ACC(r0);
            }
        }
        float inv = deg_inv[node];
        a0 *= inv; a1 *= inv; a2 *= inv; a3 *= inv;
        a4 *= inv; a5 *= inv; a6 *= inv; a7 *= inv;
    }
#undef ACC

    // pack mean row into swizzled LDS tile
    {
        uint4 o;
        o.x = (u32)f2bf(a0) | ((u32)f2bf(a1) << 16);
        o.y = (u32)f2bf(a2) | ((u32)f2bf(a3) << 16);
        o.z = (u32)f2bf(a4) | ((u32)f2bf(a5) << 16);
        o.w = (u32)f2bf(a6) | ((u32)f2bf(a7) << 16);
        int chunk = sub ^ (nloc & 7);
        *(uint4*)&tile[nloc * 128 + chunk * 8] = o;
    }
    __syncthreads();

    // MFMA phase
    const int fr = sub;
    const int kq = grp << 3;
    bf16x8 aF0[4], aF1[4];
    int rnode = wlid[fr];
    int safe_r = rnode < 0 ? 0 : rnode;
    const u16* ph = h + (size_t)safe_r * DIM + kq;
#pragma unroll
    for (int kt = 0; kt < 4; ++kt) {
        int c = (grp + kt * 4) ^ (fr & 7);
        aF0[kt] = *(const bf16x8*)&tile[fr * 128 + c * 8];
        aF1[kt] = *(const bf16x8*)(ph + kt * 32);
    }
#pragma unroll
    for (int q = 0; q < 2; ++q) {
        int nt = wid * 2 + q;
        const u16* pwl = Wl + (size_t)(nt * 16 + fr) * DIM + kq;
        const u16* pwr = Wr + (size_t)(nt * 16 + fr) * DIM + kq;
        f32x4 acc = {0.f, 0.f, 0.f, 0.f};
#pragma unroll
        for (int kt = 0; kt < 4; ++kt) {
            bf16x8 w = *(const bf16x8*)(pwl + kt * 32);
            acc = __builtin_amdgcn_mfma_f32_16x16x32_bf16(aF0[kt], w, acc, 0, 0, 0);
        }
#pragma unroll
        for (int kt = 0; kt < 4; ++kt) {
            bf16x8 w = *(const bf16x8*)(pwr + kt * 32);
            acc = __builtin_amdgcn_mfma_f32_16x16x32_bf16(aF1[kt], w, acc, 0, 0, 0);
        }
        int col = nt * 16 + fr;
        float b = bias[col];
#pragma unroll
        for (int j = 0; j < 4; ++j) {
            int onode = wlid[(grp << 2) + j];
            if (onode >= 0) {
                float v = acc[j] + b;
                if (RELU) v = fmaxf(v, 0.f);
                out[(size_t)onode * DIM + col] = f2bf(v);
            }
        }
    }
}

// ---------------- head: softmax -> log_softmax -> NLL mean (+finalize) ----------------

__global__ __launch_bounds__(256) void k_head(
    const u16* __restrict__ h3, const int* __restrict__ batch,
    const int* __restrict__ labels, const float* __restrict__ Wlin,
    const float* __restrict__ blin, float* __restrict__ accum,
    int* __restrict__ hcount, float* __restrict__ out) {
    __shared__ float wsh[256];
    __shared__ float red[4];
    int t = threadIdx.x;
    wsh[t] = Wlin[t];
    __syncthreads();

    int lane = t & 63;
    int g    = lane >> 4;
    int sub  = lane & 15;
    int wv   = (blockIdx.x * 256 + t) >> 6;
    int samp = wv * 4 + g;

    float contrib = 0.f;
    float z0 = 0.f, z1 = 0.f;
    int n = 0;
    if (samp < N_BATCH) {
        n = batch[samp];
        uint4 u = *(const uint4*)(h3 + (size_t)n * DIM + sub * 8);
        const u32* uw = (const u32*)&u;
        int cb = sub * 8;
#pragma unroll
        for (int q = 0; q < 4; ++q) {
            float hlo = bf2f((u16)(uw[q] & 0xffffu));
            float hhi = bf2f((u16)(uw[q] >> 16));
            z0 += hlo * wsh[cb + q * 2]       + hhi * wsh[cb + q * 2 + 1];
            z1 += hlo * wsh[128 + cb + q * 2] + hhi * wsh[128 + cb + q * 2 + 1];
        }
    }
#pragma unroll
    for (int off = 8; off > 0; off >>= 1) {
        z0 += __shfl_xor(z0, off);
        z1 += __shfl_xor(z1, off);
    }
    if (samp < N_BATCH) {
        z0 += blin[0]; z1 += blin[1];
        float m  = fmaxf(z0, z1);
        float e0 = expf(z0 - m), e1 = expf(z1 - m);
        float s  = e0 + e1;
        float p0 = e0 / s, p1 = e1 / s;
        float m2  = fmaxf(p0, p1);
        float lse = m2 + logf(expf(p0 - m2) + expf(p1 - m2));
        int lab = labels[n];
        float lp = ((lab == 0) ? p0 : p1) - lse;
        if (sub == 0) contrib = -lp * (1.0f / (float)N_BATCH);
    }
#pragma unroll
    for (int off = 16; off < 64; off <<= 1) contrib += __shfl_xor(contrib, off);
    if (lane == 0) red[t >> 6] = contrib;
    __syncthreads();
    if (t == 0) {
        atomicAdd(accum, red[0] + red[1] + red[2] + red[3]);
        __threadfence();
        int c = atomicAdd(hcount, 1);
        if (c == (int)gridDim.x - 1) {
            float v = atomicAdd(accum, 0.0f);
            out[0] = v;
        }
    }
}

// ---------------- launch ----------------

extern "C" void kernel_launch(void* const* d_in, const int* in_sizes, int n_in,
                              void* d_out, int out_size, void* d_ws, size_t ws_size,
                              hipStream_t stream) {
    const float* x    = (const float*)d_in[0];
    const int*   eidx = (const int*)d_in[1];
    const int*   batch  = (const int*)d_in[2];
    const int*   labels = (const int*)d_in[3];
    const float* W1l = (const float*)d_in[4];
    const float* b1  = (const float*)d_in[5];
    const float* W1r = (const float*)d_in[6];
    const float* W2l = (const float*)d_in[7];
    const float* b2  = (const float*)d_in[8];
    const float* W2r = (const float*)d_in[9];
    const float* W3l = (const float*)d_in[10];
    const float* b3  = (const float*)d_in[11];
    const float* W3r = (const float*)d_in[12];
    const float* Wlin = (const float*)d_in[13];
    const float* blin = (const float*)d_in[14];

    const int* src = eidx;
    const int* dst = eidx + N_EDGES;

    size_t off = 0;
    auto alloc = [&](size_t bytes) -> char* {
        off = (off + 511) & ~(size_t)511;
        char* p = (char*)d_ws + off;
        off += bytes;
        return p;
    };
    int*   bcur    = (int*)  alloc(NBUCK * 4);
    int*   bbase   = (int*)  alloc(NBUCK * 4);
    int*   row_ptr = (int*)  alloc(N_NODES * 4);
    int*   deg     = (int*)  alloc(N_NODES * 4);
    float* deg_inv = (float*)alloc(N_NODES * 4);
    int*   csr_src = (int*)  alloc(N_EDGES * 4);
    u64*   ebuf    = (u64*)  alloc((size_t)NBUCK * BCAP * 8);
    u16*   wb      = (u16*)  alloc(6 * DIM * DIM * 2);
    u16*   xb      = (u16*)  alloc((size_t)MPAD * DIM * 2);   // reused as bufB
    u16*   bufA    = (u16*)  alloc((size_t)MPAD * DIM * 2);
    u8*    mask    = (u8*)   alloc(N_NODES);
    int*   h1g     = (int*)  alloc(NBIN * 4);
    int*   h3g     = (int*)  alloc(NBIN * 4);
    int*   wl1     = (int*)  alloc(MPAD * 4);
    int*   wl3     = (int*)  alloc(MPAD * 4);
    int*   n3      = (int*)  alloc(4);
    float* accum   = (float*)alloc(4);
    int*   hcount  = (int*)  alloc(4);

    u16* bufB = xb;

    u16* w1l = wb + 0 * DIM * DIM;
    u16* w1r = wb + 1 * DIM * DIM;
    u16* w2l = wb + 2 * DIM * DIM;
    u16* w2r = wb + 3 * DIM * DIM;
    u16* w3l = wb + 4 * DIM * DIM;
    u16* w3r = wb + 5 * DIM * DIM;

    const int NB196 = (N_NODES + 255) / 256;      // 196
    const int PB    = (N_EDGES + 4095) / 4096;    // 196
    const int MB    = (N_BATCH + 255) / 256;      // 98
    const int CXB   = MPAD * 16 / 256;            // 3128
    const int CWB   = 6 * DIM * DIM / 256;        // 384
    const int SGB   = N_NODES / 16;               // 3125 (exact)
    const int HB2   = (N_BATCH + 15) / 16;        // 1563

    k_init<<<NB196, 256, 0, stream>>>(bcur, accum, hcount, mask, h1g, h3g);
    k_part<<<PB, 256, 0, stream>>>(src, dst, bcur, ebuf);
    k_bscan<<<1, 64, 0, stream>>>(bcur, bbase);
    k_mark<<<MB, 256, 0, stream>>>(batch, mask);
    k_build<<<NBUCK, 256, 0, stream>>>(ebuf, bcur, bbase, mask, row_ptr, deg,
                                       deg_inv, csr_src, h1g, h3g);
    k_dscan<<<1, 64, 0, stream>>>(h1g, h3g, n3);
    k_dscatter<<<NB196, 256, 0, stream>>>(deg, mask, h1g, h3g, wl1, wl3);

    k_cast_x<<<CXB, 256, 0, stream>>>(x, xb);
    k_cast_w<<<CWB, 256, 0, stream>>>(W1l, W1r, W2l, W2r, W3l, W3r, wb);

    k_sage<true, false><<<SGB, 256, 0, stream>>>(xb, csr_src, row_ptr, deg, deg_inv,
                                                 wl1, n3, w1l, w1r, b1, bufA);
    k_sage<true, false><<<SGB, 256, 0, stream>>>(bufA, csr_src, row_ptr, deg, deg_inv,
                                                 wl1, n3, w2l, w2r, b2, bufB);
    k_sage<false, true><<<SGB, 256, 0, stream>>>(bufB, csr_src, row_ptr, deg, deg_inv,
                                                 wl3, n3, w3l, w3r, b3, bufA);

    k_head<<<HB2, 256, 0, stream>>>(bufA, batch, labels, Wlin, blin,
                                    accum, hcount, (float*)d_out);
}

// Round 9
// 191.323 us; speedup vs baseline: 3.7651x; 1.1431x over previous
//
#include <hip/hip_runtime.h>
#include <hip/hip_bf16.h>

#define N_NODES 50000
#define MPAD    50048
#define N_EDGES 800000
#define DIM     128
#define N_BATCH 25000
#define NBUCK   196        // ceil(50000/256) buckets of 256 dst nodes
#define BCAP    8192       // per-bucket capacity (mean 4096, sigma 64)
#define NBIN    64         // degree bins for counting sort

typedef unsigned short u16;
typedef unsigned int   u32;
typedef unsigned char  u8;
typedef unsigned long long u64;

typedef __attribute__((ext_vector_type(8))) short bf16x8;
typedef __attribute__((ext_vector_type(4))) float f32x4;
typedef __attribute__((ext_vector_type(2))) float f32x2;

static __device__ __forceinline__ float bf2f(u16 u) {
    union { u32 i; float f; } v; v.i = ((u32)u) << 16; return v.f;
}
static __device__ __forceinline__ u16 f2bf(float f) {
    union { float f; u32 i; } v; v.f = f;
    u32 x = v.i;
    u32 r = x + 0x7fffu + ((x >> 16) & 1u);   // RTNE
    return (u16)(r >> 16);
}
// pack 2 f32 -> 2 fp8 (e4m3, OCP on gfx950); HI selects dest half (imm required)
template <bool HI>
static __device__ __forceinline__ u32 pk8(float a, float b, u32 old) {
    return (u32)__builtin_amdgcn_cvt_pk_fp8_f32(a, b, (int)old, HI);
}

// ---------------- init: cursors, accumulators, masks, bins ----------------

__global__ void k_init(int* bcur, float* accum, int* hcount, u8* mask,
                       int* c1g, int* c3g, int* o1g, int* o3g) {
    int gid = blockIdx.x * 256 + threadIdx.x;
    if (gid < NBUCK) bcur[gid] = gid * BCAP;
    if (gid < NBIN) { c1g[gid] = 0; c3g[gid] = 0; o1g[gid] = 0; o3g[gid] = 0; }
    if (gid < N_NODES) mask[gid] = 0;
    if (gid == 0) { accum[0] = 0.f; hcount[0] = 0; }
}

// ---- fused setup: edge partition | cast x -> bf16+fp8 | cast W | mark ----
// blocks [0,196): k_part; [196,3324): cast_x; [3324,3708): cast_w; [3708,3806): mark

#define SB_PART 196
#define SB_CX   3324
#define SB_CW   3708
#define SB_MK   3806

__global__ __launch_bounds__(256) void k_setup(
    const int* __restrict__ src, const int* __restrict__ dst,
    int* __restrict__ bcur, u64* __restrict__ ebuf,
    const float* __restrict__ x, u16* __restrict__ xb, u8* __restrict__ x8,
    const float* __restrict__ W1l, const float* __restrict__ W1r,
    const float* __restrict__ W2l, const float* __restrict__ W2r,
    const float* __restrict__ W3l, const float* __restrict__ W3r,
    u16* __restrict__ wout,
    const int* __restrict__ batch, u8* __restrict__ mask) {
    __shared__ int hist[NBUCK];
    __shared__ int lbase[NBUCK];
    __shared__ int gdelta[NBUCK];
    __shared__ u64 stage[4096];
    __shared__ int gaddr[4096];
    int bid = blockIdx.x;
    int t = threadIdx.x;

    if (bid < SB_PART) {
        for (int i = t; i < NBUCK; i += 256) hist[i] = 0;
        __syncthreads();

        int base = bid * 4096;
        int cnt = N_EDGES - base; if (cnt > 4096) cnt = 4096; if (cnt < 0) cnt = 0;

        int es[16], ed[16], rr[16];
#pragma unroll
        for (int k = 0; k < 16; ++k) {
            int i = t + (k << 8);
            bool ok = i < cnt;
            int e = ok ? (base + i) : 0;
            int s = src[e], d = dst[e];
            es[k] = s; ed[k] = d;
            int r = -1;
            if (ok) r = atomicAdd(&hist[d >> 8], 1);
            rr[k] = r;
        }
        __syncthreads();

        if (t < 64) {
            int run = 0;
            for (int c = 0; c < 4; ++c) {
                int idx = c * 64 + t;
                int v = (idx < NBUCK) ? hist[idx] : 0;
                int orig = v;
                for (int off = 1; off < 64; off <<= 1) {
                    int u = __shfl_up(v, off);
                    if (t >= off) v += u;
                }
                int tot = __shfl(v, 63);
                if (idx < NBUCK) lbase[idx] = run + v - orig;
                run += tot;
            }
        }
        __syncthreads();

        if (t < NBUCK) {
            int c = hist[t];
            int g = atomicAdd(&bcur[t], c);
            gdelta[t] = g - lbase[t];
        }
        __syncthreads();

#pragma unroll
        for (int k = 0; k < 16; ++k) {
            if (rr[k] >= 0) {
                int b = ed[k] >> 8;
                int slot = lbase[b] + rr[k];
                stage[slot] = (((u64)(u32)ed[k]) << 32) | (u32)es[k];
                gaddr[slot] = gdelta[b] + slot;
            }
        }
        __syncthreads();

        for (int i = t; i < cnt; i += 256) {
            ebuf[gaddr[i]] = stage[i];
        }
    } else if (bid < SB_CX) {
        int gid = (bid - SB_PART) * 256 + t;
        int row = gid >> 4;
        int c8  = (gid & 15) << 3;
        u32 outw[4];
        u32 w0 = 0, w1 = 0;
        if (row < N_NODES) {
            const float4* p = (const float4*)(x + (size_t)row * DIM + c8);
            float4 v0 = p[0], v1 = p[1];
            outw[0] = (u32)f2bf(v0.x) | ((u32)f2bf(v0.y) << 16);
            outw[1] = (u32)f2bf(v0.z) | ((u32)f2bf(v0.w) << 16);
            outw[2] = (u32)f2bf(v1.x) | ((u32)f2bf(v1.y) << 16);
            outw[3] = (u32)f2bf(v1.z) | ((u32)f2bf(v1.w) << 16);
            w0 = pk8<false>(v0.x, v0.y, 0); w0 = pk8<true>(v0.z, v0.w, w0);
            w1 = pk8<false>(v1.x, v1.y, 0); w1 = pk8<true>(v1.z, v1.w, w1);
        } else {
            outw[0] = outw[1] = outw[2] = outw[3] = 0;
        }
        *(uint4*)(xb + (size_t)row * DIM + c8) = *(uint4*)outw;
        uint2 o8; o8.x = w0; o8.y = w1;
        *(uint2*)(x8 + (size_t)row * DIM + c8) = o8;
    } else if (bid < SB_CW) {
        int i = (bid - SB_CX) * 256 + t;
        int mat = i >> 14, off = i & 16383;
        const float* s = (mat == 0) ? W1l : (mat == 1) ? W1r : (mat == 2) ? W2l
                       : (mat == 3) ? W2r : (mat == 4) ? W3l : W3r;
        wout[i] = f2bf(s[off]);
    } else {
        int s = (bid - SB_CW) * 256 + t;
        if (s < N_BATCH) mask[batch[s]] = 1;
    }
}

// ---- per-bucket: self bucket-base scan + degrees + row_ptr + csr + deg hist ----

__global__ __launch_bounds__(256) void k_build(const u64* __restrict__ ebuf,
                                               const int* __restrict__ bcur,
                                               const u8* __restrict__ mask,
                                               int* __restrict__ row_ptr,
                                               int* __restrict__ deg,
                                               float* __restrict__ deg_inv,
                                               int* __restrict__ csr_src,
                                               int* __restrict__ c1g,
                                               int* __restrict__ c3g) {
    __shared__ int cnt256[256];
    __shared__ int sh[256];
    __shared__ int cur[256];
    __shared__ int bh1[NBIN];
    __shared__ int bh3[NBIN];
    __shared__ int shbase;
    int b  = blockIdx.x;
    int t  = threadIdx.x;
    int n0 = b << 8;
    cnt256[t] = 0;
    if (t < NBIN) { bh1[t] = 0; bh3[t] = 0; }
    // bucket base = sum of counts of buckets < b (wave 0)
    if (t < 64) {
        int s = 0;
        for (int i = t; i < b; i += 64) s += bcur[i] - i * BCAP;
#pragma unroll
        for (int off = 32; off > 0; off >>= 1) s += __shfl_xor(s, off);
        if (t == 0) shbase = s;
    }
    __syncthreads();
    int bbase = shbase;

    int cnt = bcur[b] - b * BCAP;
    const u64* eb = ebuf + (size_t)b * BCAP;
    for (int i = t; i < cnt; i += 256) {
        int d = (int)(eb[i] >> 32);
        atomicAdd(&cnt256[d - n0], 1);
    }
    __syncthreads();

    int myc = cnt256[t];
    sh[t] = myc;
    __syncthreads();
    for (int off = 1; off < 256; off <<= 1) {
        int x = (t >= off) ? sh[t - off] : 0;
        __syncthreads();
        sh[t] += x;
        __syncthreads();
    }
    int rp = bbase + sh[t] - myc;
    int n  = n0 + t;
    if (n < N_NODES) {
        row_ptr[n] = rp;
        deg[n]     = myc;
        deg_inv[n] = 1.0f / (float)(myc < 1 ? 1 : myc);
        int bin = myc < NBIN ? myc : NBIN - 1;
        atomicAdd(&bh1[bin], 1);
        if (mask[n]) atomicAdd(&bh3[bin], 1);
    }
    cur[t] = rp;
    __syncthreads();

    for (int i = t; i < cnt; i += 256) {
        u64 p = eb[i];
        int d = (int)(p >> 32);
        int s = (int)(u32)p;
        int pos = atomicAdd(&cur[d - n0], 1);
        csr_src[pos] = s;
    }
    __syncthreads();
    if (t < NBIN) {
        if (bh1[t]) atomicAdd(&c1g[t], bh1[t]);
        if (bh3[t]) atomicAdd(&c3g[t], bh3[t]);
    }
}

// ---- counting-sort scatter (self-scanning): nodes into degree-sorted worklists ----

__global__ __launch_bounds__(256) void k_dscatter(const int* __restrict__ deg,
                                                  const u8* __restrict__ mask,
                                                  const int* __restrict__ c1g,
                                                  const int* __restrict__ c3g,
                                                  int* __restrict__ o1g,
                                                  int* __restrict__ o3g,
                                                  int* __restrict__ wl1,
                                                  int* __restrict__ wl3,
                                                  int* __restrict__ n3) {
    __shared__ int bh1[NBIN], bh3[NBIN], bb1[NBIN], bb3[NBIN];
    int t = threadIdx.x;
    int n = blockIdx.x * 256 + t;
    if (t < NBIN) { bh1[t] = 0; bh3[t] = 0; }
    __syncthreads();
    bool valid = n < N_NODES;
    int d = 0, r1 = -1, r3 = -1;
    if (valid) {
        d = deg[n]; if (d >= NBIN) d = NBIN - 1;
        r1 = atomicAdd(&bh1[d], 1);
        if (mask[n]) r3 = atomicAdd(&bh3[d], 1);
    }
    __syncthreads();
    if (t < 64) {
        int v1 = c1g[t], v3 = c3g[t];
        int i1 = v1, i3 = v3;
        for (int off = 1; off < 64; off <<= 1) {
            int u1 = __shfl_up(i1, off);
            int u3 = __shfl_up(i3, off);
            if (t >= off) { i1 += u1; i3 += u3; }
        }
        int res1 = atomicAdd(&o1g[t], bh1[t]);
        int res3 = atomicAdd(&o3g[t], bh3[t]);
        bb1[t] = (i1 - v1) + res1;
        bb3[t] = (i3 - v3) + res3;
        if (blockIdx.x == 0 && t == 63) n3[0] = i3;
    }
    __syncthreads();
    if (valid) {
        wl1[bb1[d] + r1] = n;
        if (r3 >= 0) wl3[bb3[d] + r3] = n;
    }
}

// ---- fused SAGE layer: fp8 gather -> mean -> LDS tile -> MFMA (bf16) ----

template <bool RELU, bool PRUNED, bool W8>
__global__ __launch_bounds__(256) void k_sage(
    const u16* __restrict__ h, const u8* __restrict__ h8,
    const int* __restrict__ csr_src,
    const int* __restrict__ row_ptr, const int* __restrict__ deg,
    const float* __restrict__ deg_inv,
    const int* __restrict__ wl, const int* __restrict__ wlN,
    const u16* __restrict__ Wl, const u16* __restrict__ Wr,
    const float* __restrict__ bias, u16* __restrict__ out,
    u8* __restrict__ out8) {
    __shared__ u16 tile[16 * 128];
    __shared__ int wlid[16];
    int nwl = PRUNED ? wlN[0] : N_NODES;
    int m0  = blockIdx.x * 16;
    if (m0 >= nwl) return;

    int t    = threadIdx.x;
    int lane = t & 63;
    int wid  = t >> 6;
    int sub  = lane & 15;
    int grp  = lane >> 4;
    int nloc = (wid << 2) + grp;
    int gb   = lane & 48;
    int node = (m0 + nloc < nwl) ? wl[m0 + nloc] : -1;
    if (sub == 0) wlid[nloc] = node;

    float a0 = 0, a1 = 0, a2 = 0, a3 = 0, a4 = 0, a5 = 0, a6 = 0, a7 = 0;

#define ACC8(r) { f32x2 p; \
    p = __builtin_amdgcn_cvt_pk_f32_fp8((r).x, false); a0 += p[0]; a1 += p[1]; \
    p = __builtin_amdgcn_cvt_pk_f32_fp8((r).x, true);  a2 += p[0]; a3 += p[1]; \
    p = __builtin_amdgcn_cvt_pk_f32_fp8((r).y, false); a4 += p[0]; a5 += p[1]; \
    p = __builtin_amdgcn_cvt_pk_f32_fp8((r).y, true);  a6 += p[0]; a7 += p[1]; }

    if (node >= 0) {
        int start = row_ptr[node];
        int cnt   = deg[node];
        for (int c0 = 0; c0 < cnt; c0 += 16) {
            int rem = cnt - c0; if (rem > 16) rem = 16;
            int sidx = 0;
            if (sub < rem) sidx = csr_src[start + c0 + sub];
            int j = 0;
            for (; j + 8 <= rem; j += 8) {
                int i0 = __shfl(sidx, gb + j);
                int i1 = __shfl(sidx, gb + j + 1);
                int i2 = __shfl(sidx, gb + j + 2);
                int i3 = __shfl(sidx, gb + j + 3);
                int i4 = __shfl(sidx, gb + j + 4);
                int i5 = __shfl(sidx, gb + j + 5);
                int i6 = __shfl(sidx, gb + j + 6);
                int i7 = __shfl(sidx, gb + j + 7);
                uint2 r0 = *(const uint2*)(h8 + (size_t)i0 * DIM + sub * 8);
                uint2 r1 = *(const uint2*)(h8 + (size_t)i1 * DIM + sub * 8);
                uint2 r2 = *(const uint2*)(h8 + (size_t)i2 * DIM + sub * 8);
                uint2 r3 = *(const uint2*)(h8 + (size_t)i3 * DIM + sub * 8);
                uint2 r4 = *(const uint2*)(h8 + (size_t)i4 * DIM + sub * 8);
                uint2 r5 = *(const uint2*)(h8 + (size_t)i5 * DIM + sub * 8);
                uint2 r6 = *(const uint2*)(h8 + (size_t)i6 * DIM + sub * 8);
                uint2 r7 = *(const uint2*)(h8 + (size_t)i7 * DIM + sub * 8);
                ACC8(r0); ACC8(r1); ACC8(r2); ACC8(r3);
                ACC8(r4); ACC8(r5); ACC8(r6); ACC8(r7);
            }
            for (; j + 4 <= rem; j += 4) {
                int i0 = __shfl(sidx, gb + j);
                int i1 = __shfl(sidx, gb + j + 1);
                int i2 = __shfl(sidx, gb + j + 2);
                int i3 = __shfl(sidx, gb + j + 3);
                uint2 r0 = *(const uint2*)(h8 + (size_t)i0 * DIM + sub * 8);
                uint2 r1 = *(const uint2*)(h8 + (size_t)i1 * DIM + sub * 8);
                uint2 r2 = *(const uint2*)(h8 + (size_t)i2 * DIM + sub * 8);
                uint2 r3 = *(const uint2*)(h8 + (size_t)i3 * DIM + sub * 8);
                ACC8(r0); ACC8(r1); ACC8(r2); ACC8(r3);
            }
            for (; j < rem; ++j) {
                int i0 = __shfl(sidx, gb + j);
                uint2 r0 = *(const uint2*)(h8 + (size_t)i0 * DIM + sub * 8);
                ACC8(r0);
            }
        }
        float inv = deg_inv[node];
        a0 *= inv; a1 *= inv; a2 *= inv; a3 *= inv;
        a4 *= inv; a5 *= inv; a6 *= inv; a7 *= inv;
    }
#undef ACC8

    // pack mean row into swizzled LDS tile
    {
        uint4 o;
        o.x = (u32)f2bf(a0) | ((u32)f2bf(a1) << 16);
        o.y = (u32)f2bf(a2) | ((u32)f2bf(a3) << 16);
        o.z = (u32)f2bf(a4) | ((u32)f2bf(a5) << 16);
        o.w = (u32)f2bf(a6) | ((u32)f2bf(a7) << 16);
        int chunk = sub ^ (nloc & 7);
        *(uint4*)&tile[nloc * 128 + chunk * 8] = o;
    }
    __syncthreads();

    // MFMA phase
    const int fr = sub;
    const int kq = grp << 3;
    bf16x8 aF0[4], aF1[4];
    int rnode = wlid[fr];
    int safe_r = rnode < 0 ? 0 : rnode;
    const u16* ph = h + (size_t)safe_r * DIM + kq;
#pragma unroll
    for (int kt = 0; kt < 4; ++kt) {
        int c = (grp + kt * 4) ^ (fr & 7);
        aF0[kt] = *(const bf16x8*)&tile[fr * 128 + c * 8];
        aF1[kt] = *(const bf16x8*)(ph + kt * 32);
    }
#pragma unroll
    for (int q = 0; q < 2; ++q) {
        int nt = wid * 2 + q;
        const u16* pwl = Wl + (size_t)(nt * 16 + fr) * DIM + kq;
        const u16* pwr = Wr + (size_t)(nt * 16 + fr) * DIM + kq;
        f32x4 acc = {0.f, 0.f, 0.f, 0.f};
#pragma unroll
        for (int kt = 0; kt < 4; ++kt) {
            bf16x8 w = *(const bf16x8*)(pwl + kt * 32);
            acc = __builtin_amdgcn_mfma_f32_16x16x32_bf16(aF0[kt], w, acc, 0, 0, 0);
        }
#pragma unroll
        for (int kt = 0; kt < 4; ++kt) {
            bf16x8 w = *(const bf16x8*)(pwr + kt * 32);
            acc = __builtin_amdgcn_mfma_f32_16x16x32_bf16(aF1[kt], w, acc, 0, 0, 0);
        }
        int col = nt * 16 + fr;
        float b = bias[col];
#pragma unroll
        for (int j = 0; j < 4; ++j) {
            int onode = wlid[(grp << 2) + j];
            if (onode >= 0) {
                float v = acc[j] + b;
                if (RELU) v = fmaxf(v, 0.f);
                out[(size_t)onode * DIM + col] = f2bf(v);
                if (W8) out8[(size_t)onode * DIM + col] = (u8)(pk8<false>(v, v, 0) & 0xffu);
            }
        }
    }
}

// ---------------- head: softmax -> log_softmax -> NLL mean (+finalize) ----------------

__global__ __launch_bounds__(256) void k_head(
    const u16* __restrict__ h3, const int* __restrict__ batch,
    const int* __restrict__ labels, const float* __restrict__ Wlin,
    const float* __restrict__ blin, float* __restrict__ accum,
    int* __restrict__ hcount, float* __restrict__ out) {
    __shared__ float wsh[256];
    __shared__ float red[4];
    int t = threadIdx.x;
    wsh[t] = Wlin[t];
    __syncthreads();

    int lane = t & 63;
    int g    = lane >> 4;
    int sub  = lane & 15;
    int wv   = (blockIdx.x * 256 + t) >> 6;
    int samp = wv * 4 + g;

    float contrib = 0.f;
    float z0 = 0.f, z1 = 0.f;
    int n = 0;
    if (samp < N_BATCH) {
        n = batch[samp];
        uint4 u = *(const uint4*)(h3 + (size_t)n * DIM + sub * 8);
        const u32* uw = (const u32*)&u;
        int cb = sub * 8;
#pragma unroll
        for (int q = 0; q < 4; ++q) {
            float hlo = bf2f((u16)(uw[q] & 0xffffu));
            float hhi = bf2f((u16)(uw[q] >> 16));
            z0 += hlo * wsh[cb + q * 2]       + hhi * wsh[cb + q * 2 + 1];
            z1 += hlo * wsh[128 + cb + q * 2] + hhi * wsh[128 + cb + q * 2 + 1];
        }
    }
#pragma unroll
    for (int off = 8; off > 0; off >>= 1) {
        z0 += __shfl_xor(z0, off);
        z1 += __shfl_xor(z1, off);
    }
    if (samp < N_BATCH) {
        z0 += blin[0]; z1 += blin[1];
        float m  = fmaxf(z0, z1);
        float e0 = expf(z0 - m), e1 = expf(z1 - m);
        float s  = e0 + e1;
        float p0 = e0 / s, p1 = e1 / s;
        float m2  = fmaxf(p0, p1);
        float lse = m2 + logf(expf(p0 - m2) + expf(p1 - m2));
        int lab = labels[n];
        float lp = ((lab == 0) ? p0 : p1) - lse;
        if (sub == 0) contrib = -lp * (1.0f / (float)N_BATCH);
    }
#pragma unroll
    for (int off = 16; off < 64; off <<= 1) contrib += __shfl_xor(contrib, off);
    if (lane == 0) red[t >> 6] = contrib;
    __syncthreads();
    if (t == 0) {
        atomicAdd(accum, red[0] + red[1] + red[2] + red[3]);
        __threadfence();
        int c = atomicAdd(hcount, 1);
        if (c == (int)gridDim.x - 1) {
            float v = atomicAdd(accum, 0.0f);
            out[0] = v;
        }
    }
}

// ---------------- launch ----------------

extern "C" void kernel_launch(void* const* d_in, const int* in_sizes, int n_in,
                              void* d_out, int out_size, void* d_ws, size_t ws_size,
                              hipStream_t stream) {
    const float* x    = (const float*)d_in[0];
    const int*   eidx = (const int*)d_in[1];
    const int*   batch  = (const int*)d_in[2];
    const int*   labels = (const int*)d_in[3];
    const float* W1l = (const float*)d_in[4];
    const float* b1  = (const float*)d_in[5];
    const float* W1r = (const float*)d_in[6];
    const float* W2l = (const float*)d_in[7];
    const float* b2  = (const float*)d_in[8];
    const float* W2r = (const float*)d_in[9];
    const float* W3l = (const float*)d_in[10];
    const float* b3  = (const float*)d_in[11];
    const float* W3r = (const float*)d_in[12];
    const float* Wlin = (const float*)d_in[13];
    const float* blin = (const float*)d_in[14];

    const int* src = eidx;
    const int* dst = eidx + N_EDGES;

    size_t off = 0;
    auto alloc = [&](size_t bytes) -> char* {
        off = (off + 511) & ~(size_t)511;
        char* p = (char*)d_ws + off;
        off += bytes;
        return p;
    };
    int*   bcur    = (int*)  alloc(NBUCK * 4);
    int*   row_ptr = (int*)  alloc(N_NODES * 4);
    int*   deg     = (int*)  alloc(N_NODES * 4);
    float* deg_inv = (float*)alloc(N_NODES * 4);
    int*   csr_src = (int*)  alloc(N_EDGES * 4);
    u64*   ebuf    = (u64*)  alloc((size_t)NBUCK * BCAP * 8);
    u16*   wb      = (u16*)  alloc(6 * DIM * DIM * 2);
    u16*   xb      = (u16*)  alloc((size_t)MPAD * DIM * 2);   // reused as bufB
    u16*   bufA    = (u16*)  alloc((size_t)MPAD * DIM * 2);
    u8*    x8      = (u8*)   alloc((size_t)MPAD * DIM);
    u8*    a8      = (u8*)   alloc((size_t)MPAD * DIM);
    u8*    b8      = (u8*)   alloc((size_t)MPAD * DIM);
    u8*    mask    = (u8*)   alloc(N_NODES);
    int*   c1g     = (int*)  alloc(NBIN * 4);
    int*   c3g     = (int*)  alloc(NBIN * 4);
    int*   o1g     = (int*)  alloc(NBIN * 4);
    int*   o3g     = (int*)  alloc(NBIN * 4);
    int*   wl1     = (int*)  alloc(MPAD * 4);
    int*   wl3     = (int*)  alloc(MPAD * 4);
    int*   n3      = (int*)  alloc(4);
    float* accum   = (float*)alloc(4);
    int*   hcount  = (int*)  alloc(4);

    u16* bufB = xb;

    u16* w1l = wb + 0 * DIM * DIM;
    u16* w1r = wb + 1 * DIM * DIM;
    u16* w2l = wb + 2 * DIM * DIM;
    u16* w2r = wb + 3 * DIM * DIM;
    u16* w3l = wb + 4 * DIM * DIM;
    u16* w3r = wb + 5 * DIM * DIM;

    const int NB196 = (N_NODES + 255) / 256;      // 196
    const int SGB   = N_NODES / 16;               // 3125
    const int HB2   = (N_BATCH + 15) / 16;        // 1563

    k_init<<<NB196, 256, 0, stream>>>(bcur, accum, hcount, mask, c1g, c3g, o1g, o3g);
    k_setup<<<SB_MK, 256, 0, stream>>>(src, dst, bcur, ebuf,
                                       x, xb, x8,
                                       W1l, W1r, W2l, W2r, W3l, W3r, wb,
                                       batch, mask);
    k_build<<<NBUCK, 256, 0, stream>>>(ebuf, bcur, mask, row_ptr, deg,
                                       deg_inv, csr_src, c1g, c3g);
    k_dscatter<<<NB196, 256, 0, stream>>>(deg, mask, c1g, c3g, o1g, o3g,
                                          wl1, wl3, n3);

    k_sage<true, false, true><<<SGB, 256, 0, stream>>>(
        xb, x8, csr_src, row_ptr, deg, deg_inv, wl1, n3, w1l, w1r, b1, bufA, a8);
    k_sage<true, false, true><<<SGB, 256, 0, stream>>>(
        bufA, a8, csr_src, row_ptr, deg, deg_inv, wl1, n3, w2l, w2r, b2, bufB, b8);
    k_sage<false, true, false><<<SGB, 256, 0, stream>>>(
        bufB, b8, csr_src, row_ptr, deg, deg_inv, wl3, n3, w3l, w3r, b3, bufA, nullptr);

    k_head<<<HB2, 256, 0, stream>>>(bufA, batch, labels, Wlin, blin,
                                    accum, hcount, (float*)d_out);
}